// Round 10
// baseline (409.168 us; speedup 1.0000x reference)
//
#include <hip/hip_runtime.h>
#include <hip/hip_bf16.h>

#define BB 8
#define NN 4096
#define FF 64
#define HH 128
#define KNN 16

// ---- reference-matching arithmetic (XLA-CPU style: FMA-contracted dot/sq) ----
__device__ __forceinline__ float sq3(float x, float y, float z) {
    return fmaf(z, z, fmaf(y, y, __fmul_rn(x, x)));
}
// dist2 = (sq_n + sq_m) - 2*dot, dot = fma chain
__device__ __forceinline__ float dist2f(float px, float py, float pz, float psq, float4 cc) {
    float t = fmaf(pz, cc.z, fmaf(py, cc.y, __fmul_rn(px, cc.x)));
    return __fsub_rn(__fadd_rn(psq, cc.w), __fmul_rn(2.0f, t));
}

// ---------------- Kernel 1: pack coords + sq norm, compute per-batch center ----------------
extern "C" __global__ __launch_bounds__(256)
void k_prep(const float* __restrict__ coords, float4* __restrict__ coords4, float* __restrict__ center) {
    const int b = blockIdx.x, tid = threadIdx.x;
    __shared__ float rx[256], ry[256], rz[256];
    float sx = 0.f, sy = 0.f, sz = 0.f;
    for (int n = tid; n < NN; n += 256) {
        const float* c = coords + (size_t)(b * NN + n) * 3;
        float x = c[0], y = c[1], z = c[2];
        coords4[b * NN + n] = make_float4(x, y, z, sq3(x, y, z));
        sx += x; sy += y; sz += z;
    }
    rx[tid] = sx; ry[tid] = sy; rz[tid] = sz;
    __syncthreads();
    for (int s = 128; s > 0; s >>= 1) {
        if (tid < s) { rx[tid] += rx[tid + s]; ry[tid] += ry[tid + s]; rz[tid] += rz[tid + s]; }
        __syncthreads();
    }
    if (tid == 0) {
        center[b * 4 + 0] = rx[0] * (1.0f / NN);
        center[b * 4 + 1] = ry[0] * (1.0f / NN);
        center[b * 4 + 2] = rz[0] * (1.0f / NN);
    }
}

// Jacobi rotation on symmetric 3x3 (exact rotations, division-safe).
#define JROT(app, aqq, apq, arp, arq, vp0, vp1, vp2, vq0, vq1, vq2) { \
    float tau_ = (aqq - app) / (2.0f * apq); \
    float tt_ = copysignf(1.0f, tau_) / (fabsf(tau_) + sqrtf(1.0f + tau_ * tau_)); \
    if (apq == 0.0f) tt_ = 0.0f; \
    float cc_ = 1.0f / sqrtf(1.0f + tt_ * tt_); \
    float ss_ = tt_ * cc_; \
    float app_n = cc_*cc_*app - 2.0f*cc_*ss_*apq + ss_*ss_*aqq; \
    float aqq_n = ss_*ss_*app + 2.0f*cc_*ss_*apq + cc_*cc_*aqq; \
    float apq_n = cc_*ss_*(app - aqq) + (cc_*cc_ - ss_*ss_)*apq; \
    float arp_n = cc_*arp - ss_*arq; \
    float arq_n = ss_*arp + cc_*arq; \
    app = app_n; aqq = aqq_n; apq = apq_n; arp = arp_n; arq = arq_n; \
    float t0_ = cc_*vp0 - ss_*vq0, t1_ = cc_*vp1 - ss_*vq1, t2_ = cc_*vp2 - ss_*vq2; \
    vq0 = ss_*vp0 + cc_*vq0; vq1 = ss_*vp1 + cc_*vq1; vq2 = ss_*vp2 + cc_*vq2; \
    vp0 = t0_; vp1 = t1_; vp2 = t2_; }

#define SWAPF(a, b) { float sw_ = a; a = b; b = sw_; }

// Bitonic sort 16 floats ascending (80 compare-exchanges, exact multiset op).
__device__ __forceinline__ void sort16(float (&d)[16]) {
#pragma unroll
    for (int k = 2; k <= 16; k <<= 1) {
#pragma unroll
        for (int j = k >> 1; j > 0; j >>= 1) {
#pragma unroll
            for (int i = 0; i < 16; i++) {
                int l = i ^ j;
                if (l > i) {
                    if ((i & k) == 0) {
                        float mn = fminf(d[i], d[l]);
                        d[l] = fmaxf(d[i], d[l]);
                        d[i] = mn;
                    } else {
                        float mx = fmaxf(d[i], d[l]);
                        d[l] = fminf(d[i], d[l]);
                        d[i] = mx;
                    }
                }
            }
        }
    }
}

// dk (asc) + d (asc) -> dk = 16 smallest of the 32, ascending (Batcher halver + clean).
__device__ __forceinline__ void merge16(float (&dk)[16], const float (&d)[16]) {
    float t[16];
#pragma unroll
    for (int i = 0; i < 16; i++) t[i] = fminf(dk[i], d[15 - i]);   // bitonic, holds lowest 16
#pragma unroll
    for (int j = 8; j > 0; j >>= 1) {
#pragma unroll
        for (int i = 0; i < 16; i++) {
            int l = i ^ j;
            if (l > i) {
                float mn = fminf(t[i], t[l]);
                t[l] = fmaxf(t[i], t[l]);
                t[i] = mn;
            }
        }
    }
#pragma unroll
    for (int i = 0; i < 16; i++) dk[i] = t[i];
}

// ---------------- Kernel 2: kNN + local geometry + non-MLP output channels ----------------
// 1024 blocks x 256 threads. Block: batch b = blk>>7, 32-point chunk (blk&127).
// Thread: point = chunk*32 + (tid&31), candidate-eighth h = tid>>5 (512 candidates each).
extern "C" __global__ __launch_bounds__(256, 4)
void k_knn(const float4* __restrict__ coords4, const float* __restrict__ center,
           float* __restrict__ invar, float* __restrict__ out) {
    const int blk = blockIdx.x;
    const int b = blk >> 7;
    const int chunk = blk & 127;
    const int tid = threadIdx.x;
    const int pid = tid & 31;
    const int h = tid >> 5;
    const int n = chunk * 32 + pid;
    const float4* __restrict__ C = coords4 + b * NN;

    __shared__ __align__(16) float4 tile[512];    // 64 cands per eighth, 8 KB
    __shared__ int ilist[256 * 24];               // per (point,eighth): 15 strict + 8 tie + pad (24 KB)
    __shared__ int cnts[256];                     // packed cs | ct<<8
    float* mb = (float*)ilist;                    // merge buffer (256*17 floats), lifetime-disjoint

    float4 me = C[n];
    const float px = me.x, py = me.y, pz = me.z, psq = me.w;
    const float INF = __builtin_inff();

    // ---- pass 1: per-eighth sorted top-16 values via batch-sort + network merge ----
    float dk[KNN];
#pragma unroll
    for (int i = 0; i < KNN; i++) dk[i] = INF;

    for (int r = 0; r < 8; r++) {
        __syncthreads();
#pragma unroll
        for (int e = tid; e < 512; e += 256) {
            int seg = e >> 6, idx = e & 63;
            tile[e] = C[seg * 512 + r * 64 + idx];
        }
        __syncthreads();
        const float4* T = &tile[h * 64];
        const int selfj = n - (h * 512 + r * 64);   // in [0,64) iff diagonal in this slice
#pragma unroll
        for (int bt = 0; bt < 4; bt++) {
            float d[16];
#pragma unroll
            for (int i = 0; i < 16; i++) {
                float4 cc = T[bt * 16 + i];          // near-uniform -> LDS broadcast
                float dd = dist2f(px, py, pz, psq, cc);
                d[i] = (bt * 16 + i) == selfj ? INF : dd;
            }
            sort16(d);
            merge16(dk, d);
        }
    }

    // ---- symmetric 8-way merge: every thread merges its 7 partners' sorted-16 ----
    __syncthreads();
#pragma unroll
    for (int i = 0; i < KNN; i++) mb[tid * 17 + i] = dk[i];
    __syncthreads();
#pragma unroll
    for (int p = 1; p < 8; p++) {
        const int partner = (((h + p) & 7) << 5) + pid;
        float o[16];
#pragma unroll
        for (int i = 0; i < KNN; i++) o[i] = mb[partner * 17 + i];
        merge16(dk, o);
    }
    const float d15 = dk[15];

    // ---- pass 2: per-eighth index collection (strict < d15; ties == d15, index order) ----
    int cs = 0, ct = 0;
    const int lbase = (pid * 8 + h) * 24;
    for (int r = 0; r < 8; r++) {
        __syncthreads();
#pragma unroll
        for (int e = tid; e < 512; e += 256) {
            int seg = e >> 6, idx = e & 63;
            tile[e] = C[seg * 512 + r * 64 + idx];
        }
        __syncthreads();
        const float4* T = &tile[h * 64];
        const int base = h * 512 + r * 64;
#pragma unroll 4
        for (int j = 0; j < 64; j++) {
            float4 cc = T[j];
            float d = dist2f(px, py, pz, psq, cc);   // bitwise identical to pass 1
            int g = base + j;
            if (g != n && d <= d15) {
                if (d < d15) {
                    if (cs < 15) ilist[lbase + cs] = g;
                    cs++;
                } else if (ct < 8) {
                    ilist[lbase + 15 + ct] = g;
                    ct++;
                }
            }
        }
    }
    cnts[pid * 8 + h] = (cs & 0xff) | (ct << 8);
    __syncthreads();

    if (h != 0) return;   // first 32 threads handle the 32 points' epilogue

    // ---- assemble exactly 16 neighbor ids: stricts (segment order = index order), then ties ----
    int s[8], t8[8], sb[8], tb[8], cum[8], tcum[8];
#pragma unroll
    for (int q = 0; q < 8; q++) {
        int cp = cnts[pid * 8 + q];
        s[q] = cp & 0xff; t8[q] = cp >> 8;
        sb[q] = (pid * 8 + q) * 24; tb[q] = sb[q] + 15;
    }
    cum[0] = s[0]; tcum[0] = t8[0];
#pragma unroll
    for (int q = 1; q < 8; q++) { cum[q] = cum[q - 1] + s[q]; tcum[q] = tcum[q - 1] + t8[q]; }

    float cxx = 0.f, cxy = 0.f, cxz = 0.f, cyy = 0.f, cyz = 0.f, czz = 0.f, radsum = 0.f;
#pragma unroll
    for (int j = 0; j < KNN; j++) {
        int addr = sb[0] + j;
#pragma unroll
        for (int q = 1; q < 8; q++)
            if (j >= cum[q - 1]) addr = sb[q] + (j - cum[q - 1]);
        int jt = j - cum[7];
        if (j >= cum[7]) addr = tb[0] + jt;
#pragma unroll
        for (int q = 1; q < 8; q++)
            if (j >= cum[7] && jt >= tcum[q - 1]) addr = tb[q] + (jt - tcum[q - 1]);
        int id = ilist[addr];
        float4 cc = C[id];
        float rx = __fsub_rn(cc.x, px), ry = __fsub_rn(cc.y, py), rz = __fsub_rn(cc.z, pz);
        cxx = __fadd_rn(cxx, __fmul_rn(rx, rx));
        cxy = __fadd_rn(cxy, __fmul_rn(rx, ry));
        cxz = __fadd_rn(cxz, __fmul_rn(rx, rz));
        cyy = __fadd_rn(cyy, __fmul_rn(ry, ry));
        cyz = __fadd_rn(cyz, __fmul_rn(ry, rz));
        czz = __fadd_rn(czz, __fmul_rn(rz, rz));
        float rr = __fadd_rn(__fadd_rn(__fmul_rn(rx, rx), __fmul_rn(ry, ry)), __fmul_rn(rz, rz));
        radsum = __fadd_rn(radsum, sqrtf(rr));
    }
    const float inv_k = 1.0f / KNN;  // exact power of two
    float a00 = cxx * inv_k, a01 = cxy * inv_k, a02 = cxz * inv_k;
    float a11 = cyy * inv_k, a12 = cyz * inv_k, a22 = czz * inv_k;

    // ---- Jacobi eigensolver, 6 cyclic sweeps ----
    float V00 = 1.f, V01 = 0.f, V02 = 0.f;
    float V10 = 0.f, V11 = 1.f, V12 = 0.f;
    float V20 = 0.f, V21 = 0.f, V22 = 1.f;
    for (int sweep = 0; sweep < 6; sweep++) {
        JROT(a00, a11, a01, a02, a12, V00, V10, V20, V01, V11, V21);
        JROT(a00, a22, a02, a01, a12, V00, V10, V20, V02, V12, V22);
        JROT(a11, a22, a12, a01, a02, V01, V11, V21, V02, V12, V22);
    }
    float e0 = a00, e1 = a11, e2 = a22;
    float x0 = V00, y0 = V10, z0 = V20;
    float x1 = V01, y1 = V11, z1 = V21;
    float x2 = V02, y2 = V12, z2 = V22;
    if (e0 > e1) { SWAPF(e0, e1); SWAPF(x0, x1); SWAPF(y0, y1); SWAPF(z0, z1); }
    if (e1 > e2) { SWAPF(e1, e2); SWAPF(x1, x2); SWAPF(y1, y2); SWAPF(z1, z2); }
    if (e0 > e1) { SWAPF(e0, e1); SWAPF(x0, x1); SWAPF(y0, y1); SWAPF(z0, z1); }

    // ---- orient + normalize normal (col 0 = smallest eigenvalue) ----
    float cx = center[b * 4 + 0], cy = center[b * 4 + 1], cz = center[b * 4 + 2];
    float ox = __fsub_rn(px, cx), oy = __fsub_rn(py, cy), oz = __fsub_rn(pz, cz);
    float dt = __fadd_rn(__fadd_rn(__fmul_rn(x0, ox), __fmul_rn(y0, oy)), __fmul_rn(z0, oz));
    float sgn = (dt >= 0.0f) ? 1.0f : -1.0f;
    x0 *= sgn; y0 *= sgn; z0 *= sgn;
    float nrm = sqrtf(__fadd_rn(__fadd_rn(__fmul_rn(x0, x0), __fmul_rn(y0, y0)), __fmul_rn(z0, z0)));
    float den = fmaxf(nrm, 1e-6f);
    x0 = x0 / den; y0 = y0 / den; z0 = z0 / den;

    // ---- invariants -> ws ----
    float radius = radsum * inv_k;
    float crad = sqrtf(__fadd_rn(__fadd_rn(__fmul_rn(ox, ox), __fmul_rn(oy, oy)), __fmul_rn(oz, oz)));
    float esum = fmaxf(__fadd_rn(__fadd_rn(e0, e1), e2), 1e-6f);
    float dom = e2 / esum;
    float* ip = invar + (size_t)(b * NN + n) * 8;
    ip[0] = e0; ip[1] = e1; ip[2] = e2; ip[3] = radius; ip[4] = crad; ip[5] = dom;
    ip[6] = 0.f; ip[7] = 0.f;

    // ---- output channels (f32). ch0 placeholder, overwritten by k_mlp ----
    float pd = __fadd_rn(__fadd_rn(__fmul_rn(px, x0), __fmul_rn(py, y0)), __fmul_rn(pz, z0));
    float4* o = (float4*)(out + (size_t)(b * NN + n) * 16);
    o[0] = make_float4(0.0f, x0, y0, -z0);
    o[1] = make_float4(-pd, x0, y0, z0);
    o[2] = make_float4(0.0f, 0.0f, 0.0f, px);
    o[3] = make_float4(py, pz, 1.0f, 0.0f);
}

// ---------------- Kernel 3: fused MLPs ----------------
__device__ __forceinline__ float gelu_exact(float x) {
    return 0.5f * x * (1.0f + erff(x * 0.70710678118654752440f));
}

// Small-K GEMM (K=6), ROWS output rows per thread.
template <int KDIM, int LDA, int ROWS>
__device__ __forceinline__ void gemm_small(const float* __restrict__ A, const float* __restrict__ W,
                                           const float* __restrict__ bias, int p0, int c0, float acc[ROWS][4]) {
    float4 bb = *(const float4*)(bias + c0);
#pragma unroll
    for (int i = 0; i < ROWS; i++) { acc[i][0] = bb.x; acc[i][1] = bb.y; acc[i][2] = bb.z; acc[i][3] = bb.w; }
#pragma unroll
    for (int k = 0; k < KDIM; k++) {
        float4 w = *(const float4*)(W + k * HH + c0);
#pragma unroll
        for (int i = 0; i < ROWS; i++) {
            float a = A[(p0 + i) * LDA + k];
            acc[i][0] = fmaf(a, w.x, acc[i][0]);
            acc[i][1] = fmaf(a, w.y, acc[i][1]);
            acc[i][2] = fmaf(a, w.z, acc[i][2]);
            acc[i][3] = fmaf(a, w.w, acc[i][3]);
        }
    }
}

// K%8==0 GEMM. Chunk-8 batch of W loads inside a NOT-unrolled loop.
// R7/R8 lesson: full unroll of this loop lets the scheduler hoist load batches
// across chunks -> register blowup -> scratch spill (FETCH 6MB -> 10.5GB, 35x slowdown).
// #pragma unroll 1 keeps the body a loop; 8 W loads amortize latency within a chunk.
// Accumulation order: ascending k per output (bitwise identical to gemm_small).
template <int KDIM, int LDA, int ROWS>
__device__ __forceinline__ void gemm_c8(const float* __restrict__ A, const float* __restrict__ W,
                                        const float* __restrict__ bias, int p0, int c0, float acc[ROWS][4]) {
    static_assert(KDIM % 8 == 0, "KDIM must be a multiple of 8");
    float4 bb = *(const float4*)(bias + c0);
#pragma unroll
    for (int i = 0; i < ROWS; i++) { acc[i][0] = bb.x; acc[i][1] = bb.y; acc[i][2] = bb.z; acc[i][3] = bb.w; }

#pragma unroll 1
    for (int kk = 0; kk < KDIM; kk += 8) {
        const float* Wk = W + kk * HH + c0;
        float4 w0 = *(const float4*)(Wk + 0 * HH);
        float4 w1 = *(const float4*)(Wk + 1 * HH);
        float4 w2 = *(const float4*)(Wk + 2 * HH);
        float4 w3 = *(const float4*)(Wk + 3 * HH);
        float4 w4 = *(const float4*)(Wk + 4 * HH);
        float4 w5 = *(const float4*)(Wk + 5 * HH);
        float4 w6 = *(const float4*)(Wk + 6 * HH);
        float4 w7 = *(const float4*)(Wk + 7 * HH);
#pragma unroll
        for (int r = 0; r < ROWS; r++) {
            const float* Ar = A + (p0 + r) * LDA + kk;
            float4 t0 = *(const float4*)(Ar);
            float4 t1 = *(const float4*)(Ar + 4);
            acc[r][0] = fmaf(t0.x, w0.x, acc[r][0]);
            acc[r][1] = fmaf(t0.x, w0.y, acc[r][1]);
            acc[r][2] = fmaf(t0.x, w0.z, acc[r][2]);
            acc[r][3] = fmaf(t0.x, w0.w, acc[r][3]);
            acc[r][0] = fmaf(t0.y, w1.x, acc[r][0]);
            acc[r][1] = fmaf(t0.y, w1.y, acc[r][1]);
            acc[r][2] = fmaf(t0.y, w1.z, acc[r][2]);
            acc[r][3] = fmaf(t0.y, w1.w, acc[r][3]);
            acc[r][0] = fmaf(t0.z, w2.x, acc[r][0]);
            acc[r][1] = fmaf(t0.z, w2.y, acc[r][1]);
            acc[r][2] = fmaf(t0.z, w2.z, acc[r][2]);
            acc[r][3] = fmaf(t0.z, w2.w, acc[r][3]);
            acc[r][0] = fmaf(t0.w, w3.x, acc[r][0]);
            acc[r][1] = fmaf(t0.w, w3.y, acc[r][1]);
            acc[r][2] = fmaf(t0.w, w3.z, acc[r][2]);
            acc[r][3] = fmaf(t0.w, w3.w, acc[r][3]);
            acc[r][0] = fmaf(t1.x, w4.x, acc[r][0]);
            acc[r][1] = fmaf(t1.x, w4.y, acc[r][1]);
            acc[r][2] = fmaf(t1.x, w4.z, acc[r][2]);
            acc[r][3] = fmaf(t1.x, w4.w, acc[r][3]);
            acc[r][0] = fmaf(t1.y, w5.x, acc[r][0]);
            acc[r][1] = fmaf(t1.y, w5.y, acc[r][1]);
            acc[r][2] = fmaf(t1.y, w5.z, acc[r][2]);
            acc[r][3] = fmaf(t1.y, w5.w, acc[r][3]);
            acc[r][0] = fmaf(t1.z, w6.x, acc[r][0]);
            acc[r][1] = fmaf(t1.z, w6.y, acc[r][1]);
            acc[r][2] = fmaf(t1.z, w6.z, acc[r][2]);
            acc[r][3] = fmaf(t1.z, w6.w, acc[r][3]);
            acc[r][0] = fmaf(t1.w, w7.x, acc[r][0]);
            acc[r][1] = fmaf(t1.w, w7.y, acc[r][1]);
            acc[r][2] = fmaf(t1.w, w7.z, acc[r][2]);
            acc[r][3] = fmaf(t1.w, w7.w, acc[r][3]);
        }
    }
}

__device__ __forceinline__ void store4f(float* dst, float a, float b, float c, float d) {
    *(float4*)dst = make_float4(a, b, c, d);
}

// TILE=16, 2048 blocks: LDS ~25.7 KB -> 5-6 blocks/CU (vs TILE=32's 51 KB -> 2-3).
// Each thread: 2 rows x 4 cols. Doubles waves/SIMD for L2-latency hiding (TLP, not
// per-thread buffering - see R7/R8 spill lesson above).
extern "C" __global__ __launch_bounds__(256, 5)
void k_mlp(const float* __restrict__ invar, const float* __restrict__ features,
           const float* __restrict__ iW1, const float* __restrict__ ib1,
           const float* __restrict__ iW2, const float* __restrict__ ib2,
           const float* __restrict__ fW1, const float* __restrict__ fb1,
           const float* __restrict__ fW2, const float* __restrict__ fb2,
           const float* __restrict__ sW1, const float* __restrict__ sb1,
           const float* __restrict__ sW2, const float* __restrict__ sb2,
           const float* __restrict__ gW, const float* __restrict__ gb,
           float* __restrict__ out) {
    const int TILE = 16;
    const int pt0 = blockIdx.x * TILE;
    const int tid = threadIdx.x;
    const int cg = tid & 31, pg = tid >> 5;
    const int c0 = cg * 4, p0 = pg * 2;

    __shared__ __align__(16) float shin[TILE * 260];   // concat(inv_h, feat_h); also hosts features tile
    __shared__ __align__(16) float bufA[TILE * 132];   // hidden scratch
    __shared__ __align__(16) float inv6[TILE * 8];     // invariants tile
    __shared__ float sc[TILE];

    if (tid < TILE * 8) {   // load invariants tile (16 x 8, padded)
        int p = tid >> 3, j = tid & 7;
        inv6[p * 8 + j] = invar[(size_t)(pt0 + p) * 8 + j];
    }
#pragma unroll
    for (int it = 0; it < 4; it++) {   // features tile (16 x 64) -> shin[:,128:192] (lifetime-disjoint)
        int idx = tid + it * 256;
        int p = idx >> 6, f = idx & 63;
        shin[p * 260 + 128 + f] = features[(size_t)(pt0 + p) * FF + f];
    }
    if (tid < TILE) sc[tid] = gb[0];
    __syncthreads();

    float acc[2][4];

    // L1a: gelu(inv @ iW1 + ib1) -> bufA
    gemm_small<6, 8, 2>(inv6, iW1, ib1, p0, c0, acc);
#pragma unroll
    for (int i = 0; i < 2; i++)
        store4f(&bufA[(p0 + i) * 132 + c0], gelu_exact(acc[i][0]), gelu_exact(acc[i][1]),
                gelu_exact(acc[i][2]), gelu_exact(acc[i][3]));
    __syncthreads();

    // L2a: bufA @ iW2 + ib2 -> shin[:, 0:128]
    gemm_c8<128, 132, 2>(bufA, iW2, ib2, p0, c0, acc);
#pragma unroll
    for (int i = 0; i < 2; i++)
        store4f(&shin[(p0 + i) * 260 + c0], acc[i][0], acc[i][1], acc[i][2], acc[i][3]);
    __syncthreads();

    // L1b: gelu(feat @ fW1 + fb1) -> bufA   (features live at shin[:,128:192])
    gemm_c8<64, 260, 2>(shin + 128, fW1, fb1, p0, c0, acc);
#pragma unroll
    for (int i = 0; i < 2; i++)
        store4f(&bufA[(p0 + i) * 132 + c0], gelu_exact(acc[i][0]), gelu_exact(acc[i][1]),
                gelu_exact(acc[i][2]), gelu_exact(acc[i][3]));
    __syncthreads();

    // L2b: bufA @ fW2 + fb2 -> shin[:, 128:256]  (overwrites features tile - done with it)
    gemm_c8<128, 132, 2>(bufA, fW2, fb2, p0, c0, acc);
#pragma unroll
    for (int i = 0; i < 2; i++)
        store4f(&shin[(p0 + i) * 260 + 128 + c0], acc[i][0], acc[i][1], acc[i][2], acc[i][3]);
    __syncthreads();

    // L1c: gelu(shin @ sW1 + sb1) -> bufA
    gemm_c8<256, 260, 2>(shin, sW1, sb1, p0, c0, acc);
#pragma unroll
    for (int i = 0; i < 2; i++)
        store4f(&bufA[(p0 + i) * 132 + c0], gelu_exact(acc[i][0]), gelu_exact(acc[i][1]),
                gelu_exact(acc[i][2]), gelu_exact(acc[i][3]));
    __syncthreads();

    // L2c: bufA @ sW2 + sb2 (in regs), then scalar = hidden @ g0_W + g0_b
    gemm_c8<128, 132, 2>(bufA, sW2, sb2, p0, c0, acc);
    float4 g = *(const float4*)(gW + c0);
#pragma unroll
    for (int i = 0; i < 2; i++) {
        float s = acc[i][0] * g.x + acc[i][1] * g.y + acc[i][2] * g.z + acc[i][3] * g.w;
        atomicAdd(&sc[p0 + i], s);
    }
    __syncthreads();
    if (tid < TILE) out[(size_t)(pt0 + tid) * 16] = sc[tid];
}

// ---------------- launcher ----------------
extern "C" void kernel_launch(void* const* d_in, const int* in_sizes, int n_in,
                              void* d_out, int out_size, void* d_ws, size_t ws_size,
                              hipStream_t stream) {
    const float* coords   = (const float*)d_in[0];
    const float* features = (const float*)d_in[1];
    const float* iW1 = (const float*)d_in[2],  * ib1 = (const float*)d_in[3];
    const float* iW2 = (const float*)d_in[4],  * ib2 = (const float*)d_in[5];
    const float* fW1 = (const float*)d_in[6],  * fb1 = (const float*)d_in[7];
    const float* fW2 = (const float*)d_in[8],  * fb2 = (const float*)d_in[9];
    const float* sW1 = (const float*)d_in[10], * sb1 = (const float*)d_in[11];
    const float* sW2 = (const float*)d_in[12], * sb2 = (const float*)d_in[13];
    const float* gW  = (const float*)d_in[14], * gb  = (const float*)d_in[15];
    float* out = (float*)d_out;

    float* ws = (float*)d_ws;
    float4* coords4 = (float4*)ws;            // B*N float4
    float* center = ws + BB * NN * 4;         // B*4 floats
    float* invar  = center + 32;              // B*N*8 floats

    hipLaunchKernelGGL(k_prep, dim3(BB), dim3(256), 0, stream, coords, coords4, center);
    hipLaunchKernelGGL(k_knn, dim3(1024), dim3(256), 0, stream, coords4, center, invar, out);
    hipLaunchKernelGGL(k_mlp, dim3(2048), dim3(256), 0, stream, invar, features,
                       iW1, ib1, iW2, ib2, fW1, fb1, fW2, fb2, sW1, sb1, sW2, sb2, gW, gb, out);
}

// Round 11
// 378.504 us; speedup vs baseline: 1.0810x; 1.0810x over previous
//
#include <hip/hip_runtime.h>
#include <hip/hip_bf16.h>

#define BB 8
#define NN 4096
#define FF 64
#define HH 128
#define KNN 16

// ---- reference-matching arithmetic (XLA-CPU style: FMA-contracted dot/sq) ----
__device__ __forceinline__ float sq3(float x, float y, float z) {
    return fmaf(z, z, fmaf(y, y, __fmul_rn(x, x)));
}
// dist2 = (sq_n + sq_m) - 2*dot, dot = fma chain
__device__ __forceinline__ float dist2f(float px, float py, float pz, float psq, float4 cc) {
    float t = fmaf(pz, cc.z, fmaf(py, cc.y, __fmul_rn(px, cc.x)));
    return __fsub_rn(__fadd_rn(psq, cc.w), __fmul_rn(2.0f, t));
}

// ---------------- Kernel 1: pack coords + sq norm, compute per-batch center ----------------
extern "C" __global__ __launch_bounds__(256)
void k_prep(const float* __restrict__ coords, float4* __restrict__ coords4, float* __restrict__ center) {
    const int b = blockIdx.x, tid = threadIdx.x;
    __shared__ float rx[256], ry[256], rz[256];
    float sx = 0.f, sy = 0.f, sz = 0.f;
    for (int n = tid; n < NN; n += 256) {
        const float* c = coords + (size_t)(b * NN + n) * 3;
        float x = c[0], y = c[1], z = c[2];
        coords4[b * NN + n] = make_float4(x, y, z, sq3(x, y, z));
        sx += x; sy += y; sz += z;
    }
    rx[tid] = sx; ry[tid] = sy; rz[tid] = sz;
    __syncthreads();
    for (int s = 128; s > 0; s >>= 1) {
        if (tid < s) { rx[tid] += rx[tid + s]; ry[tid] += ry[tid + s]; rz[tid] += rz[tid + s]; }
        __syncthreads();
    }
    if (tid == 0) {
        center[b * 4 + 0] = rx[0] * (1.0f / NN);
        center[b * 4 + 1] = ry[0] * (1.0f / NN);
        center[b * 4 + 2] = rz[0] * (1.0f / NN);
    }
}

// Jacobi rotation on symmetric 3x3 (exact rotations, division-safe).
#define JROT(app, aqq, apq, arp, arq, vp0, vp1, vp2, vq0, vq1, vq2) { \
    float tau_ = (aqq - app) / (2.0f * apq); \
    float tt_ = copysignf(1.0f, tau_) / (fabsf(tau_) + sqrtf(1.0f + tau_ * tau_)); \
    if (apq == 0.0f) tt_ = 0.0f; \
    float cc_ = 1.0f / sqrtf(1.0f + tt_ * tt_); \
    float ss_ = tt_ * cc_; \
    float app_n = cc_*cc_*app - 2.0f*cc_*ss_*apq + ss_*ss_*aqq; \
    float aqq_n = ss_*ss_*app + 2.0f*cc_*ss_*apq + cc_*cc_*aqq; \
    float apq_n = cc_*ss_*(app - aqq) + (cc_*cc_ - ss_*ss_)*apq; \
    float arp_n = cc_*arp - ss_*arq; \
    float arq_n = ss_*arp + cc_*arq; \
    app = app_n; aqq = aqq_n; apq = apq_n; arp = arp_n; arq = arq_n; \
    float t0_ = cc_*vp0 - ss_*vq0, t1_ = cc_*vp1 - ss_*vq1, t2_ = cc_*vp2 - ss_*vq2; \
    vq0 = ss_*vp0 + cc_*vq0; vq1 = ss_*vp1 + cc_*vq1; vq2 = ss_*vp2 + cc_*vq2; \
    vp0 = t0_; vp1 = t1_; vp2 = t2_; }

#define SWAPF(a, b) { float sw_ = a; a = b; b = sw_; }

// Bitonic sort 16 floats ascending (80 compare-exchanges, exact multiset op).
__device__ __forceinline__ void sort16(float (&d)[16]) {
#pragma unroll
    for (int k = 2; k <= 16; k <<= 1) {
#pragma unroll
        for (int j = k >> 1; j > 0; j >>= 1) {
#pragma unroll
            for (int i = 0; i < 16; i++) {
                int l = i ^ j;
                if (l > i) {
                    if ((i & k) == 0) {
                        float mn = fminf(d[i], d[l]);
                        d[l] = fmaxf(d[i], d[l]);
                        d[i] = mn;
                    } else {
                        float mx = fmaxf(d[i], d[l]);
                        d[l] = fminf(d[i], d[l]);
                        d[i] = mx;
                    }
                }
            }
        }
    }
}

// dk (asc) + d (asc) -> dk = 16 smallest of the 32, ascending (Batcher halver + clean).
__device__ __forceinline__ void merge16(float (&dk)[16], const float (&d)[16]) {
    float t[16];
#pragma unroll
    for (int i = 0; i < 16; i++) t[i] = fminf(dk[i], d[15 - i]);   // bitonic, holds lowest 16
#pragma unroll
    for (int j = 8; j > 0; j >>= 1) {
#pragma unroll
        for (int i = 0; i < 16; i++) {
            int l = i ^ j;
            if (l > i) {
                float mn = fminf(t[i], t[l]);
                t[l] = fmaxf(t[i], t[l]);
                t[i] = mn;
            }
        }
    }
#pragma unroll
    for (int i = 0; i < 16; i++) dk[i] = t[i];
}

// ---------------- Kernel 2: kNN + local geometry + non-MLP output channels ----------------
// 1024 blocks x 256 threads. Block: batch b = blk>>7, 32-point chunk (blk&127).
// Thread: point = chunk*32 + (tid&31), candidate-eighth h = tid>>5 (512 candidates each).
extern "C" __global__ __launch_bounds__(256, 4)
void k_knn(const float4* __restrict__ coords4, const float* __restrict__ center,
           float* __restrict__ invar, float* __restrict__ out) {
    const int blk = blockIdx.x;
    const int b = blk >> 7;
    const int chunk = blk & 127;
    const int tid = threadIdx.x;
    const int pid = tid & 31;
    const int h = tid >> 5;
    const int n = chunk * 32 + pid;
    const float4* __restrict__ C = coords4 + b * NN;

    __shared__ __align__(16) float4 tile[512];    // 64 cands per eighth, 8 KB
    __shared__ int ilist[256 * 24];               // per (point,eighth): 15 strict + 8 tie + pad (24 KB)
    __shared__ int cnts[256];                     // packed cs | ct<<8
    float* mb = (float*)ilist;                    // merge buffer (256*17 floats), lifetime-disjoint

    float4 me = C[n];
    const float px = me.x, py = me.y, pz = me.z, psq = me.w;
    const float INF = __builtin_inff();

    // ---- pass 1: per-eighth sorted top-16 values via batch-sort + network merge ----
    float dk[KNN];
#pragma unroll
    for (int i = 0; i < KNN; i++) dk[i] = INF;

    for (int r = 0; r < 8; r++) {
        __syncthreads();
#pragma unroll
        for (int e = tid; e < 512; e += 256) {
            int seg = e >> 6, idx = e & 63;
            tile[e] = C[seg * 512 + r * 64 + idx];
        }
        __syncthreads();
        const float4* T = &tile[h * 64];
        const int selfj = n - (h * 512 + r * 64);   // in [0,64) iff diagonal in this slice
#pragma unroll
        for (int bt = 0; bt < 4; bt++) {
            float d[16];
#pragma unroll
            for (int i = 0; i < 16; i++) {
                float4 cc = T[bt * 16 + i];          // near-uniform -> LDS broadcast
                float dd = dist2f(px, py, pz, psq, cc);
                d[i] = (bt * 16 + i) == selfj ? INF : dd;
            }
            sort16(d);
            merge16(dk, d);
        }
    }

    // ---- symmetric 8-way merge: every thread merges its 7 partners' sorted-16 ----
    __syncthreads();
#pragma unroll
    for (int i = 0; i < KNN; i++) mb[tid * 17 + i] = dk[i];
    __syncthreads();
#pragma unroll
    for (int p = 1; p < 8; p++) {
        const int partner = (((h + p) & 7) << 5) + pid;
        float o[16];
#pragma unroll
        for (int i = 0; i < KNN; i++) o[i] = mb[partner * 17 + i];
        merge16(dk, o);
    }
    const float d15 = dk[15];

    // ---- pass 2: per-eighth index collection (strict < d15; ties == d15, index order) ----
    int cs = 0, ct = 0;
    const int lbase = (pid * 8 + h) * 24;
    for (int r = 0; r < 8; r++) {
        __syncthreads();
#pragma unroll
        for (int e = tid; e < 512; e += 256) {
            int seg = e >> 6, idx = e & 63;
            tile[e] = C[seg * 512 + r * 64 + idx];
        }
        __syncthreads();
        const float4* T = &tile[h * 64];
        const int base = h * 512 + r * 64;
#pragma unroll 4
        for (int j = 0; j < 64; j++) {
            float4 cc = T[j];
            float d = dist2f(px, py, pz, psq, cc);   // bitwise identical to pass 1
            int g = base + j;
            if (g != n && d <= d15) {
                if (d < d15) {
                    if (cs < 15) ilist[lbase + cs] = g;
                    cs++;
                } else if (ct < 8) {
                    ilist[lbase + 15 + ct] = g;
                    ct++;
                }
            }
        }
    }
    cnts[pid * 8 + h] = (cs & 0xff) | (ct << 8);
    __syncthreads();

    if (h != 0) return;   // first 32 threads handle the 32 points' epilogue

    // ---- assemble exactly 16 neighbor ids: stricts (segment order = index order), then ties ----
    int s[8], t8[8], sb[8], tb[8], cum[8], tcum[8];
#pragma unroll
    for (int q = 0; q < 8; q++) {
        int cp = cnts[pid * 8 + q];
        s[q] = cp & 0xff; t8[q] = cp >> 8;
        sb[q] = (pid * 8 + q) * 24; tb[q] = sb[q] + 15;
    }
    cum[0] = s[0]; tcum[0] = t8[0];
#pragma unroll
    for (int q = 1; q < 8; q++) { cum[q] = cum[q - 1] + s[q]; tcum[q] = tcum[q - 1] + t8[q]; }

    float cxx = 0.f, cxy = 0.f, cxz = 0.f, cyy = 0.f, cyz = 0.f, czz = 0.f, radsum = 0.f;
#pragma unroll
    for (int j = 0; j < KNN; j++) {
        int addr = sb[0] + j;
#pragma unroll
        for (int q = 1; q < 8; q++)
            if (j >= cum[q - 1]) addr = sb[q] + (j - cum[q - 1]);
        int jt = j - cum[7];
        if (j >= cum[7]) addr = tb[0] + jt;
#pragma unroll
        for (int q = 1; q < 8; q++)
            if (j >= cum[7] && jt >= tcum[q - 1]) addr = tb[q] + (jt - tcum[q - 1]);
        int id = ilist[addr];
        float4 cc = C[id];
        float rx = __fsub_rn(cc.x, px), ry = __fsub_rn(cc.y, py), rz = __fsub_rn(cc.z, pz);
        cxx = __fadd_rn(cxx, __fmul_rn(rx, rx));
        cxy = __fadd_rn(cxy, __fmul_rn(rx, ry));
        cxz = __fadd_rn(cxz, __fmul_rn(rx, rz));
        cyy = __fadd_rn(cyy, __fmul_rn(ry, ry));
        cyz = __fadd_rn(cyz, __fmul_rn(ry, rz));
        czz = __fadd_rn(czz, __fmul_rn(rz, rz));
        float rr = __fadd_rn(__fadd_rn(__fmul_rn(rx, rx), __fmul_rn(ry, ry)), __fmul_rn(rz, rz));
        radsum = __fadd_rn(radsum, sqrtf(rr));
    }
    const float inv_k = 1.0f / KNN;  // exact power of two
    float a00 = cxx * inv_k, a01 = cxy * inv_k, a02 = cxz * inv_k;
    float a11 = cyy * inv_k, a12 = cyz * inv_k, a22 = czz * inv_k;

    // ---- Jacobi eigensolver, 6 cyclic sweeps ----
    float V00 = 1.f, V01 = 0.f, V02 = 0.f;
    float V10 = 0.f, V11 = 1.f, V12 = 0.f;
    float V20 = 0.f, V21 = 0.f, V22 = 1.f;
    for (int sweep = 0; sweep < 6; sweep++) {
        JROT(a00, a11, a01, a02, a12, V00, V10, V20, V01, V11, V21);
        JROT(a00, a22, a02, a01, a12, V00, V10, V20, V02, V12, V22);
        JROT(a11, a22, a12, a01, a02, V01, V11, V21, V02, V12, V22);
    }
    float e0 = a00, e1 = a11, e2 = a22;
    float x0 = V00, y0 = V10, z0 = V20;
    float x1 = V01, y1 = V11, z1 = V21;
    float x2 = V02, y2 = V12, z2 = V22;
    if (e0 > e1) { SWAPF(e0, e1); SWAPF(x0, x1); SWAPF(y0, y1); SWAPF(z0, z1); }
    if (e1 > e2) { SWAPF(e1, e2); SWAPF(x1, x2); SWAPF(y1, y2); SWAPF(z1, z2); }
    if (e0 > e1) { SWAPF(e0, e1); SWAPF(x0, x1); SWAPF(y0, y1); SWAPF(z0, z1); }

    // ---- orient + normalize normal (col 0 = smallest eigenvalue) ----
    float cx = center[b * 4 + 0], cy = center[b * 4 + 1], cz = center[b * 4 + 2];
    float ox = __fsub_rn(px, cx), oy = __fsub_rn(py, cy), oz = __fsub_rn(pz, cz);
    float dt = __fadd_rn(__fadd_rn(__fmul_rn(x0, ox), __fmul_rn(y0, oy)), __fmul_rn(z0, oz));
    float sgn = (dt >= 0.0f) ? 1.0f : -1.0f;
    x0 *= sgn; y0 *= sgn; z0 *= sgn;
    float nrm = sqrtf(__fadd_rn(__fadd_rn(__fmul_rn(x0, x0), __fmul_rn(y0, y0)), __fmul_rn(z0, z0)));
    float den = fmaxf(nrm, 1e-6f);
    x0 = x0 / den; y0 = y0 / den; z0 = z0 / den;

    // ---- invariants -> ws ----
    float radius = radsum * inv_k;
    float crad = sqrtf(__fadd_rn(__fadd_rn(__fmul_rn(ox, ox), __fmul_rn(oy, oy)), __fmul_rn(oz, oz)));
    float esum = fmaxf(__fadd_rn(__fadd_rn(e0, e1), e2), 1e-6f);
    float dom = e2 / esum;
    float* ip = invar + (size_t)(b * NN + n) * 8;
    ip[0] = e0; ip[1] = e1; ip[2] = e2; ip[3] = radius; ip[4] = crad; ip[5] = dom;
    ip[6] = 0.f; ip[7] = 0.f;

    // ---- output channels (f32). ch0 placeholder, overwritten by k_mlp ----
    float pd = __fadd_rn(__fadd_rn(__fmul_rn(px, x0), __fmul_rn(py, y0)), __fmul_rn(pz, z0));
    float4* o = (float4*)(out + (size_t)(b * NN + n) * 16);
    o[0] = make_float4(0.0f, x0, y0, -z0);
    o[1] = make_float4(-pd, x0, y0, z0);
    o[2] = make_float4(0.0f, 0.0f, 0.0f, px);
    o[3] = make_float4(py, pz, 1.0f, 0.0f);
}

// ---------------- Kernel 3: fused MLPs ----------------
__device__ __forceinline__ float gelu_exact(float x) {
    return 0.5f * x * (1.0f + erff(x * 0.70710678118654752440f));
}

// Small-K GEMM (K=6), ROWS output rows per thread.
template <int KDIM, int LDA, int ROWS>
__device__ __forceinline__ void gemm_small(const float* __restrict__ A, const float* __restrict__ W,
                                           const float* __restrict__ bias, int p0, int c0, float acc[ROWS][4]) {
    float4 bb = *(const float4*)(bias + c0);
#pragma unroll
    for (int i = 0; i < ROWS; i++) { acc[i][0] = bb.x; acc[i][1] = bb.y; acc[i][2] = bb.z; acc[i][3] = bb.w; }
#pragma unroll
    for (int k = 0; k < KDIM; k++) {
        float4 w = *(const float4*)(W + k * HH + c0);
#pragma unroll
        for (int i = 0; i < ROWS; i++) {
            float a = A[(p0 + i) * LDA + k];
            acc[i][0] = fmaf(a, w.x, acc[i][0]);
            acc[i][1] = fmaf(a, w.y, acc[i][1]);
            acc[i][2] = fmaf(a, w.z, acc[i][2]);
            acc[i][3] = fmaf(a, w.w, acc[i][3]);
        }
    }
}

// K%8==0 GEMM. Chunk-8 batch of W loads inside a NOT-unrolled loop.
// R7/R8 lesson: full unroll of this loop lets the scheduler hoist load batches
// across chunks -> register blowup -> scratch spill (FETCH 6MB -> 10.5GB, 35x slowdown).
// R10 lesson: the binding constraint is L2 BW on W streams (replication = TILE/ROWS);
// ROWS=8 halves W traffic vs ROWS=4 and gives 512 FMAs per 8 loads (self-hiding).
// Accumulation order: ascending k per output (bitwise identical to gemm_small).
template <int KDIM, int LDA, int ROWS>
__device__ __forceinline__ void gemm_c8(const float* __restrict__ A, const float* __restrict__ W,
                                        const float* __restrict__ bias, int p0, int c0, float acc[ROWS][4]) {
    static_assert(KDIM % 8 == 0, "KDIM must be a multiple of 8");
    float4 bb = *(const float4*)(bias + c0);
#pragma unroll
    for (int i = 0; i < ROWS; i++) { acc[i][0] = bb.x; acc[i][1] = bb.y; acc[i][2] = bb.z; acc[i][3] = bb.w; }

#pragma unroll 1
    for (int kk = 0; kk < KDIM; kk += 8) {
        const float* Wk = W + kk * HH + c0;
        float4 w0 = *(const float4*)(Wk + 0 * HH);
        float4 w1 = *(const float4*)(Wk + 1 * HH);
        float4 w2 = *(const float4*)(Wk + 2 * HH);
        float4 w3 = *(const float4*)(Wk + 3 * HH);
        float4 w4 = *(const float4*)(Wk + 4 * HH);
        float4 w5 = *(const float4*)(Wk + 5 * HH);
        float4 w6 = *(const float4*)(Wk + 6 * HH);
        float4 w7 = *(const float4*)(Wk + 7 * HH);
#pragma unroll
        for (int r = 0; r < ROWS; r++) {
            const float* Ar = A + (p0 + r) * LDA + kk;
            float4 t0 = *(const float4*)(Ar);
            float4 t1 = *(const float4*)(Ar + 4);
            acc[r][0] = fmaf(t0.x, w0.x, acc[r][0]);
            acc[r][1] = fmaf(t0.x, w0.y, acc[r][1]);
            acc[r][2] = fmaf(t0.x, w0.z, acc[r][2]);
            acc[r][3] = fmaf(t0.x, w0.w, acc[r][3]);
            acc[r][0] = fmaf(t0.y, w1.x, acc[r][0]);
            acc[r][1] = fmaf(t0.y, w1.y, acc[r][1]);
            acc[r][2] = fmaf(t0.y, w1.z, acc[r][2]);
            acc[r][3] = fmaf(t0.y, w1.w, acc[r][3]);
            acc[r][0] = fmaf(t0.z, w2.x, acc[r][0]);
            acc[r][1] = fmaf(t0.z, w2.y, acc[r][1]);
            acc[r][2] = fmaf(t0.z, w2.z, acc[r][2]);
            acc[r][3] = fmaf(t0.z, w2.w, acc[r][3]);
            acc[r][0] = fmaf(t0.w, w3.x, acc[r][0]);
            acc[r][1] = fmaf(t0.w, w3.y, acc[r][1]);
            acc[r][2] = fmaf(t0.w, w3.z, acc[r][2]);
            acc[r][3] = fmaf(t0.w, w3.w, acc[r][3]);
            acc[r][0] = fmaf(t1.x, w4.x, acc[r][0]);
            acc[r][1] = fmaf(t1.x, w4.y, acc[r][1]);
            acc[r][2] = fmaf(t1.x, w4.z, acc[r][2]);
            acc[r][3] = fmaf(t1.x, w4.w, acc[r][3]);
            acc[r][0] = fmaf(t1.y, w5.x, acc[r][0]);
            acc[r][1] = fmaf(t1.y, w5.y, acc[r][1]);
            acc[r][2] = fmaf(t1.y, w5.z, acc[r][2]);
            acc[r][3] = fmaf(t1.y, w5.w, acc[r][3]);
            acc[r][0] = fmaf(t1.z, w6.x, acc[r][0]);
            acc[r][1] = fmaf(t1.z, w6.y, acc[r][1]);
            acc[r][2] = fmaf(t1.z, w6.z, acc[r][2]);
            acc[r][3] = fmaf(t1.z, w6.w, acc[r][3]);
            acc[r][0] = fmaf(t1.w, w7.x, acc[r][0]);
            acc[r][1] = fmaf(t1.w, w7.y, acc[r][1]);
            acc[r][2] = fmaf(t1.w, w7.z, acc[r][2]);
            acc[r][3] = fmaf(t1.w, w7.w, acc[r][3]);
        }
    }
}

__device__ __forceinline__ void store4f(float* dst, float a, float b, float c, float d) {
    *(float4*)dst = make_float4(a, b, c, d);
}

// TILE=32, 128 threads/block (cg 32 cols x pg 4 row-groups, ROWS=8), 1024 blocks.
// W L2 traffic halves vs ROWS=4 (replication TILE/ROWS = 4), and each chunk has
// 512 straight-line FMAs per 8 W loads -> latency self-hiding without buffering.
extern "C" __global__ __launch_bounds__(128, 2)
void k_mlp(const float* __restrict__ invar, const float* __restrict__ features,
           const float* __restrict__ iW1, const float* __restrict__ ib1,
           const float* __restrict__ iW2, const float* __restrict__ ib2,
           const float* __restrict__ fW1, const float* __restrict__ fb1,
           const float* __restrict__ fW2, const float* __restrict__ fb2,
           const float* __restrict__ sW1, const float* __restrict__ sb1,
           const float* __restrict__ sW2, const float* __restrict__ sb2,
           const float* __restrict__ gW, const float* __restrict__ gb,
           float* __restrict__ out) {
    const int TILE = 32;
    const int pt0 = blockIdx.x * TILE;
    const int tid = threadIdx.x;
    const int cg = tid & 31, pg = tid >> 5;      // pg in [0,4)
    const int c0 = cg * 4, p0 = pg * 8;          // ROWS=8

    // LDS ~51.3 KB -> 3 blocks/CU (6 waves).
    __shared__ __align__(16) float shin[TILE * 260];   // concat(inv_h, feat_h); also hosts features tile
    __shared__ __align__(16) float bufA[TILE * 132];   // hidden scratch
    __shared__ __align__(16) float inv6[TILE * 8];     // invariants tile
    __shared__ float sc[TILE];

#pragma unroll
    for (int it = 0; it < 2; it++) {   // invariants tile (32 x 8)
        int idx = tid + it * 128;
        int p = idx >> 3, j = idx & 7;
        inv6[p * 8 + j] = invar[(size_t)(pt0 + p) * 8 + j];
    }
#pragma unroll
    for (int it = 0; it < 16; it++) {  // features tile (32 x 64) -> shin[:,128:192] (lifetime-disjoint)
        int idx = tid + it * 128;
        int p = idx >> 6, f = idx & 63;
        shin[p * 260 + 128 + f] = features[(size_t)(pt0 + p) * FF + f];
    }
    if (tid < TILE) sc[tid] = gb[0];
    __syncthreads();

    float acc[8][4];

    // L1a: gelu(inv @ iW1 + ib1) -> bufA
    gemm_small<6, 8, 8>(inv6, iW1, ib1, p0, c0, acc);
#pragma unroll
    for (int i = 0; i < 8; i++)
        store4f(&bufA[(p0 + i) * 132 + c0], gelu_exact(acc[i][0]), gelu_exact(acc[i][1]),
                gelu_exact(acc[i][2]), gelu_exact(acc[i][3]));
    __syncthreads();

    // L2a: bufA @ iW2 + ib2 -> shin[:, 0:128]
    gemm_c8<128, 132, 8>(bufA, iW2, ib2, p0, c0, acc);
#pragma unroll
    for (int i = 0; i < 8; i++)
        store4f(&shin[(p0 + i) * 260 + c0], acc[i][0], acc[i][1], acc[i][2], acc[i][3]);
    __syncthreads();

    // L1b: gelu(feat @ fW1 + fb1) -> bufA   (features live at shin[:,128:192])
    gemm_c8<64, 260, 8>(shin + 128, fW1, fb1, p0, c0, acc);
#pragma unroll
    for (int i = 0; i < 8; i++)
        store4f(&bufA[(p0 + i) * 132 + c0], gelu_exact(acc[i][0]), gelu_exact(acc[i][1]),
                gelu_exact(acc[i][2]), gelu_exact(acc[i][3]));
    __syncthreads();

    // L2b: bufA @ fW2 + fb2 -> shin[:, 128:256]  (overwrites features tile - done with it)
    gemm_c8<128, 132, 8>(bufA, fW2, fb2, p0, c0, acc);
#pragma unroll
    for (int i = 0; i < 8; i++)
        store4f(&shin[(p0 + i) * 260 + 128 + c0], acc[i][0], acc[i][1], acc[i][2], acc[i][3]);
    __syncthreads();

    // L1c: gelu(shin @ sW1 + sb1) -> bufA
    gemm_c8<256, 260, 8>(shin, sW1, sb1, p0, c0, acc);
#pragma unroll
    for (int i = 0; i < 8; i++)
        store4f(&bufA[(p0 + i) * 132 + c0], gelu_exact(acc[i][0]), gelu_exact(acc[i][1]),
                gelu_exact(acc[i][2]), gelu_exact(acc[i][3]));
    __syncthreads();

    // L2c: bufA @ sW2 + sb2 (in regs), then scalar = hidden @ g0_W + g0_b
    gemm_c8<128, 132, 8>(bufA, sW2, sb2, p0, c0, acc);
    float4 g = *(const float4*)(gW + c0);
#pragma unroll
    for (int i = 0; i < 8; i++) {
        float s = acc[i][0] * g.x + acc[i][1] * g.y + acc[i][2] * g.z + acc[i][3] * g.w;
        atomicAdd(&sc[p0 + i], s);
    }
    __syncthreads();
    if (tid < TILE) out[(size_t)(pt0 + tid) * 16] = sc[tid];
}

// ---------------- launcher ----------------
extern "C" void kernel_launch(void* const* d_in, const int* in_sizes, int n_in,
                              void* d_out, int out_size, void* d_ws, size_t ws_size,
                              hipStream_t stream) {
    const float* coords   = (const float*)d_in[0];
    const float* features = (const float*)d_in[1];
    const float* iW1 = (const float*)d_in[2],  * ib1 = (const float*)d_in[3];
    const float* iW2 = (const float*)d_in[4],  * ib2 = (const float*)d_in[5];
    const float* fW1 = (const float*)d_in[6],  * fb1 = (const float*)d_in[7];
    const float* fW2 = (const float*)d_in[8],  * fb2 = (const float*)d_in[9];
    const float* sW1 = (const float*)d_in[10], * sb1 = (const float*)d_in[11];
    const float* sW2 = (const float*)d_in[12], * sb2 = (const float*)d_in[13];
    const float* gW  = (const float*)d_in[14], * gb  = (const float*)d_in[15];
    float* out = (float*)d_out;

    float* ws = (float*)d_ws;
    float4* coords4 = (float4*)ws;            // B*N float4
    float* center = ws + BB * NN * 4;         // B*4 floats
    float* invar  = center + 32;              // B*N*8 floats

    hipLaunchKernelGGL(k_prep, dim3(BB), dim3(256), 0, stream, coords, coords4, center);
    hipLaunchKernelGGL(k_knn, dim3(1024), dim3(256), 0, stream, coords4, center, invar, out);
    hipLaunchKernelGGL(k_mlp, dim3(1024), dim3(128), 0, stream, invar, features,
                       iW1, ib1, iW2, ib2, fW1, fb1, fW2, fb2, sW1, sb1, sW2, sb2, gW, gb, out);
}

// Round 12
// 343.926 us; speedup vs baseline: 1.1897x; 1.1005x over previous
//
#include <hip/hip_runtime.h>
#include <hip/hip_bf16.h>

#define BB 8
#define NN 4096
#define FF 64
#define HH 128
#define KNN 16

// ---- reference-matching arithmetic (XLA-CPU style: FMA-contracted dot/sq) ----
__device__ __forceinline__ float sq3(float x, float y, float z) {
    return fmaf(z, z, fmaf(y, y, __fmul_rn(x, x)));
}
// dist2 = (sq_n + sq_m) - 2*dot, dot = fma chain
__device__ __forceinline__ float dist2f(float px, float py, float pz, float psq, float4 cc) {
    float t = fmaf(pz, cc.z, fmaf(py, cc.y, __fmul_rn(px, cc.x)));
    return __fsub_rn(__fadd_rn(psq, cc.w), __fmul_rn(2.0f, t));
}

// ---------------- Kernel 1: pack coords + sq norm, compute per-batch center ----------------
extern "C" __global__ __launch_bounds__(256)
void k_prep(const float* __restrict__ coords, float4* __restrict__ coords4, float* __restrict__ center) {
    const int b = blockIdx.x, tid = threadIdx.x;
    __shared__ float rx[256], ry[256], rz[256];
    float sx = 0.f, sy = 0.f, sz = 0.f;
    for (int n = tid; n < NN; n += 256) {
        const float* c = coords + (size_t)(b * NN + n) * 3;
        float x = c[0], y = c[1], z = c[2];
        coords4[b * NN + n] = make_float4(x, y, z, sq3(x, y, z));
        sx += x; sy += y; sz += z;
    }
    rx[tid] = sx; ry[tid] = sy; rz[tid] = sz;
    __syncthreads();
    for (int s = 128; s > 0; s >>= 1) {
        if (tid < s) { rx[tid] += rx[tid + s]; ry[tid] += ry[tid + s]; rz[tid] += rz[tid + s]; }
        __syncthreads();
    }
    if (tid == 0) {
        center[b * 4 + 0] = rx[0] * (1.0f / NN);
        center[b * 4 + 1] = ry[0] * (1.0f / NN);
        center[b * 4 + 2] = rz[0] * (1.0f / NN);
    }
}

// Jacobi rotation on symmetric 3x3 (exact rotations, division-safe).
#define JROT(app, aqq, apq, arp, arq, vp0, vp1, vp2, vq0, vq1, vq2) { \
    float tau_ = (aqq - app) / (2.0f * apq); \
    float tt_ = copysignf(1.0f, tau_) / (fabsf(tau_) + sqrtf(1.0f + tau_ * tau_)); \
    if (apq == 0.0f) tt_ = 0.0f; \
    float cc_ = 1.0f / sqrtf(1.0f + tt_ * tt_); \
    float ss_ = tt_ * cc_; \
    float app_n = cc_*cc_*app - 2.0f*cc_*ss_*apq + ss_*ss_*aqq; \
    float aqq_n = ss_*ss_*app + 2.0f*cc_*ss_*apq + cc_*cc_*aqq; \
    float apq_n = cc_*ss_*(app - aqq) + (cc_*cc_ - ss_*ss_)*apq; \
    float arp_n = cc_*arp - ss_*arq; \
    float arq_n = ss_*arp + cc_*arq; \
    app = app_n; aqq = aqq_n; apq = apq_n; arp = arp_n; arq = arq_n; \
    float t0_ = cc_*vp0 - ss_*vq0, t1_ = cc_*vp1 - ss_*vq1, t2_ = cc_*vp2 - ss_*vq2; \
    vq0 = ss_*vp0 + cc_*vq0; vq1 = ss_*vp1 + cc_*vq1; vq2 = ss_*vp2 + cc_*vq2; \
    vp0 = t0_; vp1 = t1_; vp2 = t2_; }

#define SWAPF(a, b) { float sw_ = a; a = b; b = sw_; }

// Bitonic sort 16 floats ascending (80 compare-exchanges, exact multiset op).
__device__ __forceinline__ void sort16(float (&d)[16]) {
#pragma unroll
    for (int k = 2; k <= 16; k <<= 1) {
#pragma unroll
        for (int j = k >> 1; j > 0; j >>= 1) {
#pragma unroll
            for (int i = 0; i < 16; i++) {
                int l = i ^ j;
                if (l > i) {
                    if ((i & k) == 0) {
                        float mn = fminf(d[i], d[l]);
                        d[l] = fmaxf(d[i], d[l]);
                        d[i] = mn;
                    } else {
                        float mx = fmaxf(d[i], d[l]);
                        d[l] = fminf(d[i], d[l]);
                        d[i] = mx;
                    }
                }
            }
        }
    }
}

// dk (asc) + d (asc) -> dk = 16 smallest of the 32, ascending (Batcher halver + clean).
__device__ __forceinline__ void merge16(float (&dk)[16], const float (&d)[16]) {
    float t[16];
#pragma unroll
    for (int i = 0; i < 16; i++) t[i] = fminf(dk[i], d[15 - i]);   // bitonic, holds lowest 16
#pragma unroll
    for (int j = 8; j > 0; j >>= 1) {
#pragma unroll
        for (int i = 0; i < 16; i++) {
            int l = i ^ j;
            if (l > i) {
                float mn = fminf(t[i], t[l]);
                t[l] = fmaxf(t[i], t[l]);
                t[i] = mn;
            }
        }
    }
#pragma unroll
    for (int i = 0; i < 16; i++) dk[i] = t[i];
}

// ---------------- Kernel 2: kNN + local geometry + non-MLP output channels ----------------
// 1024 blocks x 256 threads. Block: batch b = blk>>7, 32-point chunk (blk&127).
// Thread: point = chunk*32 + (tid&31), candidate-eighth h = tid>>5 (512 candidates each).
extern "C" __global__ __launch_bounds__(256, 4)
void k_knn(const float4* __restrict__ coords4, const float* __restrict__ center,
           float* __restrict__ invar, float* __restrict__ out) {
    const int blk = blockIdx.x;
    const int b = blk >> 7;
    const int chunk = blk & 127;
    const int tid = threadIdx.x;
    const int pid = tid & 31;
    const int h = tid >> 5;
    const int n = chunk * 32 + pid;
    const float4* __restrict__ C = coords4 + b * NN;

    __shared__ __align__(16) float4 tile[512];    // 64 cands per eighth, 8 KB
    __shared__ int ilist[256 * 24];               // per (point,eighth): 15 strict + 8 tie + pad (24 KB)
    __shared__ int cnts[256];                     // packed cs | ct<<8
    float* mb = (float*)ilist;                    // merge buffer (256*17 floats), lifetime-disjoint

    float4 me = C[n];
    const float px = me.x, py = me.y, pz = me.z, psq = me.w;
    const float INF = __builtin_inff();

    // ---- pass 1: per-eighth sorted top-16 values via batch-sort + network merge ----
    float dk[KNN];
#pragma unroll
    for (int i = 0; i < KNN; i++) dk[i] = INF;

    for (int r = 0; r < 8; r++) {
        __syncthreads();
#pragma unroll
        for (int e = tid; e < 512; e += 256) {
            int seg = e >> 6, idx = e & 63;
            tile[e] = C[seg * 512 + r * 64 + idx];
        }
        __syncthreads();
        const float4* T = &tile[h * 64];
        const int selfj = n - (h * 512 + r * 64);   // in [0,64) iff diagonal in this slice
#pragma unroll
        for (int bt = 0; bt < 4; bt++) {
            float d[16];
#pragma unroll
            for (int i = 0; i < 16; i++) {
                float4 cc = T[bt * 16 + i];          // near-uniform -> LDS broadcast
                float dd = dist2f(px, py, pz, psq, cc);
                d[i] = (bt * 16 + i) == selfj ? INF : dd;
            }
            sort16(d);
            merge16(dk, d);
        }
    }

    // ---- symmetric 8-way merge: every thread merges its 7 partners' sorted-16 ----
    __syncthreads();
#pragma unroll
    for (int i = 0; i < KNN; i++) mb[tid * 17 + i] = dk[i];
    __syncthreads();
#pragma unroll
    for (int p = 1; p < 8; p++) {
        const int partner = (((h + p) & 7) << 5) + pid;
        float o[16];
#pragma unroll
        for (int i = 0; i < KNN; i++) o[i] = mb[partner * 17 + i];
        merge16(dk, o);
    }
    const float d15 = dk[15];

    // ---- pass 2: per-eighth index collection (strict < d15; ties == d15, index order) ----
    int cs = 0, ct = 0;
    const int lbase = (pid * 8 + h) * 24;
    for (int r = 0; r < 8; r++) {
        __syncthreads();
#pragma unroll
        for (int e = tid; e < 512; e += 256) {
            int seg = e >> 6, idx = e & 63;
            tile[e] = C[seg * 512 + r * 64 + idx];
        }
        __syncthreads();
        const float4* T = &tile[h * 64];
        const int base = h * 512 + r * 64;
#pragma unroll 4
        for (int j = 0; j < 64; j++) {
            float4 cc = T[j];
            float d = dist2f(px, py, pz, psq, cc);   // bitwise identical to pass 1
            int g = base + j;
            if (g != n && d <= d15) {
                if (d < d15) {
                    if (cs < 15) ilist[lbase + cs] = g;
                    cs++;
                } else if (ct < 8) {
                    ilist[lbase + 15 + ct] = g;
                    ct++;
                }
            }
        }
    }
    cnts[pid * 8 + h] = (cs & 0xff) | (ct << 8);
    __syncthreads();

    if (h != 0) return;   // first 32 threads handle the 32 points' epilogue

    // ---- assemble exactly 16 neighbor ids: stricts (segment order = index order), then ties ----
    int s[8], t8[8], sb[8], tb[8], cum[8], tcum[8];
#pragma unroll
    for (int q = 0; q < 8; q++) {
        int cp = cnts[pid * 8 + q];
        s[q] = cp & 0xff; t8[q] = cp >> 8;
        sb[q] = (pid * 8 + q) * 24; tb[q] = sb[q] + 15;
    }
    cum[0] = s[0]; tcum[0] = t8[0];
#pragma unroll
    for (int q = 1; q < 8; q++) { cum[q] = cum[q - 1] + s[q]; tcum[q] = tcum[q - 1] + t8[q]; }

    float cxx = 0.f, cxy = 0.f, cxz = 0.f, cyy = 0.f, cyz = 0.f, czz = 0.f, radsum = 0.f;
#pragma unroll
    for (int j = 0; j < KNN; j++) {
        int addr = sb[0] + j;
#pragma unroll
        for (int q = 1; q < 8; q++)
            if (j >= cum[q - 1]) addr = sb[q] + (j - cum[q - 1]);
        int jt = j - cum[7];
        if (j >= cum[7]) addr = tb[0] + jt;
#pragma unroll
        for (int q = 1; q < 8; q++)
            if (j >= cum[7] && jt >= tcum[q - 1]) addr = tb[q] + (jt - tcum[q - 1]);
        int id = ilist[addr];
        float4 cc = C[id];
        float rx = __fsub_rn(cc.x, px), ry = __fsub_rn(cc.y, py), rz = __fsub_rn(cc.z, pz);
        cxx = __fadd_rn(cxx, __fmul_rn(rx, rx));
        cxy = __fadd_rn(cxy, __fmul_rn(rx, ry));
        cxz = __fadd_rn(cxz, __fmul_rn(rx, rz));
        cyy = __fadd_rn(cyy, __fmul_rn(ry, ry));
        cyz = __fadd_rn(cyz, __fmul_rn(ry, rz));
        czz = __fadd_rn(czz, __fmul_rn(rz, rz));
        float rr = __fadd_rn(__fadd_rn(__fmul_rn(rx, rx), __fmul_rn(ry, ry)), __fmul_rn(rz, rz));
        radsum = __fadd_rn(radsum, sqrtf(rr));
    }
    const float inv_k = 1.0f / KNN;  // exact power of two
    float a00 = cxx * inv_k, a01 = cxy * inv_k, a02 = cxz * inv_k;
    float a11 = cyy * inv_k, a12 = cyz * inv_k, a22 = czz * inv_k;

    // ---- Jacobi eigensolver, 6 cyclic sweeps ----
    float V00 = 1.f, V01 = 0.f, V02 = 0.f;
    float V10 = 0.f, V11 = 1.f, V12 = 0.f;
    float V20 = 0.f, V21 = 0.f, V22 = 1.f;
    for (int sweep = 0; sweep < 6; sweep++) {
        JROT(a00, a11, a01, a02, a12, V00, V10, V20, V01, V11, V21);
        JROT(a00, a22, a02, a01, a12, V00, V10, V20, V02, V12, V22);
        JROT(a11, a22, a12, a01, a02, V01, V11, V21, V02, V12, V22);
    }
    float e0 = a00, e1 = a11, e2 = a22;
    float x0 = V00, y0 = V10, z0 = V20;
    float x1 = V01, y1 = V11, z1 = V21;
    float x2 = V02, y2 = V12, z2 = V22;
    if (e0 > e1) { SWAPF(e0, e1); SWAPF(x0, x1); SWAPF(y0, y1); SWAPF(z0, z1); }
    if (e1 > e2) { SWAPF(e1, e2); SWAPF(x1, x2); SWAPF(y1, y2); SWAPF(z1, z2); }
    if (e0 > e1) { SWAPF(e0, e1); SWAPF(x0, x1); SWAPF(y0, y1); SWAPF(z0, z1); }

    // ---- orient + normalize normal (col 0 = smallest eigenvalue) ----
    float cx = center[b * 4 + 0], cy = center[b * 4 + 1], cz = center[b * 4 + 2];
    float ox = __fsub_rn(px, cx), oy = __fsub_rn(py, cy), oz = __fsub_rn(pz, cz);
    float dt = __fadd_rn(__fadd_rn(__fmul_rn(x0, ox), __fmul_rn(y0, oy)), __fmul_rn(z0, oz));
    float sgn = (dt >= 0.0f) ? 1.0f : -1.0f;
    x0 *= sgn; y0 *= sgn; z0 *= sgn;
    float nrm = sqrtf(__fadd_rn(__fadd_rn(__fmul_rn(x0, x0), __fmul_rn(y0, y0)), __fmul_rn(z0, z0)));
    float den = fmaxf(nrm, 1e-6f);
    x0 = x0 / den; y0 = y0 / den; z0 = z0 / den;

    // ---- invariants -> ws ----
    float radius = radsum * inv_k;
    float crad = sqrtf(__fadd_rn(__fadd_rn(__fmul_rn(ox, ox), __fmul_rn(oy, oy)), __fmul_rn(oz, oz)));
    float esum = fmaxf(__fadd_rn(__fadd_rn(e0, e1), e2), 1e-6f);
    float dom = e2 / esum;
    float* ip = invar + (size_t)(b * NN + n) * 8;
    ip[0] = e0; ip[1] = e1; ip[2] = e2; ip[3] = radius; ip[4] = crad; ip[5] = dom;
    ip[6] = 0.f; ip[7] = 0.f;

    // ---- output channels (f32). ch0 placeholder, overwritten by k_mlp ----
    float pd = __fadd_rn(__fadd_rn(__fmul_rn(px, x0), __fmul_rn(py, y0)), __fmul_rn(pz, z0));
    float4* o = (float4*)(out + (size_t)(b * NN + n) * 16);
    o[0] = make_float4(0.0f, x0, y0, -z0);
    o[1] = make_float4(-pd, x0, y0, z0);
    o[2] = make_float4(0.0f, 0.0f, 0.0f, px);
    o[3] = make_float4(py, pz, 1.0f, 0.0f);
}

// ---------------- Kernel 3: fused MLPs ----------------
__device__ __forceinline__ float gelu_exact(float x) {
    return 0.5f * x * (1.0f + erff(x * 0.70710678118654752440f));
}

// Small-K GEMM (K=6), direct global W reads (tiny).
template <int KDIM, int LDA>
__device__ __forceinline__ void gemm_small(const float* __restrict__ A, const float* __restrict__ W,
                                           const float* __restrict__ bias, int p0, int c0, float acc[4][4]) {
    float4 bb = *(const float4*)(bias + c0);
#pragma unroll
    for (int i = 0; i < 4; i++) { acc[i][0] = bb.x; acc[i][1] = bb.y; acc[i][2] = bb.z; acc[i][3] = bb.w; }
#pragma unroll
    for (int k = 0; k < KDIM; k++) {
        float4 w = *(const float4*)(W + k * HH + c0);
#pragma unroll
        for (int i = 0; i < 4; i++) {
            float a = A[(p0 + i) * LDA + k];
            acc[i][0] = fmaf(a, w.x, acc[i][0]);
            acc[i][1] = fmaf(a, w.y, acc[i][1]);
            acc[i][2] = fmaf(a, w.z, acc[i][2]);
            acc[i][3] = fmaf(a, w.w, acc[i][3]);
        }
    }
}

// K%8==0 GEMM with W streamed through DOUBLE-BUFFERED LDS chunks.
// R7/R8 lesson: no full unroll of the chunk loop (scratch spill); prefetch value
// is a single float4 scalar, not an array.
// R10/R11 lesson: neither occupancy nor W-traffic volume was the constraint —
// per-thread W L2 round-trips serialized each chunk. Here: one coalesced
// float4/thread stages chunk kk+8 into LDS while chunk kk's FMAs run; W reads
// become LDS broadcasts; one barrier/chunk, covered by the 2nd resident block.
// Accumulation order: ascending k per output (bitwise identical to before).
template <int KDIM, int LDA>
__device__ __forceinline__ void gemm_lds(const float* __restrict__ A, const float* __restrict__ Wg,
                                         const float* __restrict__ bias, float* __restrict__ wbuf,
                                         int tid, int p0, int c0, float acc[4][4]) {
    static_assert(KDIM % 8 == 0, "KDIM must be a multiple of 8");
    float4 bb = *(const float4*)(bias + c0);
#pragma unroll
    for (int i = 0; i < 4; i++) { acc[i][0] = bb.x; acc[i][1] = bb.y; acc[i][2] = bb.z; acc[i][3] = bb.w; }

    const int wrow = tid >> 5;            // 8 rows, one per 32-thread group
    const int wc4 = (tid & 31) * 4;       // 32 float4-columns
    // preload chunk 0 into buffer 0
    {
        float4 v = *(const float4*)(Wg + wrow * HH + wc4);
        *(float4*)(wbuf + wrow * HH + wc4) = v;
    }
    __syncthreads();
    int pb = 0;
#pragma unroll 1
    for (int kk = 0; kk < KDIM; kk += 8) {
        float4 vn;
        const bool more = (kk + 8 < KDIM);
        if (more) vn = *(const float4*)(Wg + (kk + 8 + wrow) * HH + wc4);   // in flight across FMAs

        const float* Wl = wbuf + pb * (8 * HH) + c0;
        float4 w0 = *(const float4*)(Wl + 0 * HH);
        float4 w1 = *(const float4*)(Wl + 1 * HH);
        float4 w2 = *(const float4*)(Wl + 2 * HH);
        float4 w3 = *(const float4*)(Wl + 3 * HH);
        float4 w4 = *(const float4*)(Wl + 4 * HH);
        float4 w5 = *(const float4*)(Wl + 5 * HH);
        float4 w6 = *(const float4*)(Wl + 6 * HH);
        float4 w7 = *(const float4*)(Wl + 7 * HH);
#pragma unroll
        for (int r = 0; r < 4; r++) {
            const float* Ar = A + (p0 + r) * LDA + kk;
            float4 t0 = *(const float4*)(Ar);
            float4 t1 = *(const float4*)(Ar + 4);
            acc[r][0] = fmaf(t0.x, w0.x, acc[r][0]);
            acc[r][1] = fmaf(t0.x, w0.y, acc[r][1]);
            acc[r][2] = fmaf(t0.x, w0.z, acc[r][2]);
            acc[r][3] = fmaf(t0.x, w0.w, acc[r][3]);
            acc[r][0] = fmaf(t0.y, w1.x, acc[r][0]);
            acc[r][1] = fmaf(t0.y, w1.y, acc[r][1]);
            acc[r][2] = fmaf(t0.y, w1.z, acc[r][2]);
            acc[r][3] = fmaf(t0.y, w1.w, acc[r][3]);
            acc[r][0] = fmaf(t0.z, w2.x, acc[r][0]);
            acc[r][1] = fmaf(t0.z, w2.y, acc[r][1]);
            acc[r][2] = fmaf(t0.z, w2.z, acc[r][2]);
            acc[r][3] = fmaf(t0.z, w2.w, acc[r][3]);
            acc[r][0] = fmaf(t0.w, w3.x, acc[r][0]);
            acc[r][1] = fmaf(t0.w, w3.y, acc[r][1]);
            acc[r][2] = fmaf(t0.w, w3.z, acc[r][2]);
            acc[r][3] = fmaf(t0.w, w3.w, acc[r][3]);
            acc[r][0] = fmaf(t1.x, w4.x, acc[r][0]);
            acc[r][1] = fmaf(t1.x, w4.y, acc[r][1]);
            acc[r][2] = fmaf(t1.x, w4.z, acc[r][2]);
            acc[r][3] = fmaf(t1.x, w4.w, acc[r][3]);
            acc[r][0] = fmaf(t1.y, w5.x, acc[r][0]);
            acc[r][1] = fmaf(t1.y, w5.y, acc[r][1]);
            acc[r][2] = fmaf(t1.y, w5.z, acc[r][2]);
            acc[r][3] = fmaf(t1.y, w5.w, acc[r][3]);
            acc[r][0] = fmaf(t1.z, w6.x, acc[r][0]);
            acc[r][1] = fmaf(t1.z, w6.y, acc[r][1]);
            acc[r][2] = fmaf(t1.z, w6.z, acc[r][2]);
            acc[r][3] = fmaf(t1.z, w6.w, acc[r][3]);
            acc[r][0] = fmaf(t1.w, w7.x, acc[r][0]);
            acc[r][1] = fmaf(t1.w, w7.y, acc[r][1]);
            acc[r][2] = fmaf(t1.w, w7.z, acc[r][2]);
            acc[r][3] = fmaf(t1.w, w7.w, acc[r][3]);
        }
        if (more) *(float4*)(wbuf + (pb ^ 1) * (8 * HH) + wrow * HH + wc4) = vn;
        __syncthreads();
        pb ^= 1;
    }
}

__device__ __forceinline__ void store4f(float* dst, float a, float b, float c, float d) {
    *(float4*)dst = make_float4(a, b, c, d);
}

// TILE=32, 256 threads (32 cg x 8 pg, ROWS=4), 1024 blocks. LDS ~58.5 KB -> 2 blocks/CU.
extern "C" __global__ __launch_bounds__(256, 2)
void k_mlp(const float* __restrict__ invar, const float* __restrict__ features,
           const float* __restrict__ iW1, const float* __restrict__ ib1,
           const float* __restrict__ iW2, const float* __restrict__ ib2,
           const float* __restrict__ fW1, const float* __restrict__ fb1,
           const float* __restrict__ fW2, const float* __restrict__ fb2,
           const float* __restrict__ sW1, const float* __restrict__ sb1,
           const float* __restrict__ sW2, const float* __restrict__ sb2,
           const float* __restrict__ gW, const float* __restrict__ gb,
           float* __restrict__ out) {
    const int TILE = 32;
    const int pt0 = blockIdx.x * TILE;
    const int tid = threadIdx.x;
    const int cg = tid & 31, pg = tid >> 5;
    const int c0 = cg * 4, p0 = pg * 4;

    // A-reads are same-address broadcasts within a pg-group; stores are contiguous:
    // no padding needed on row strides (R10/R11: SQ_LDS_BANK_CONFLICT == 0).
    __shared__ __align__(16) float shin[TILE * 256];   // concat(inv_h, feat_h); hosts features tile
    __shared__ __align__(16) float bufA[TILE * 128];   // hidden scratch
    __shared__ __align__(16) float wbuf[2 * 8 * HH];   // W chunk double-buffer, 8 KB
    __shared__ __align__(16) float inv6[TILE * 8];     // invariants tile
    __shared__ float sc[TILE];

    if (tid < TILE * 8) {   // invariants tile (32 x 8)
        int p = tid >> 3, j = tid & 7;
        inv6[p * 8 + j] = invar[(size_t)(pt0 + p) * 8 + j];
    }
#pragma unroll
    for (int it = 0; it < 8; it++) {   // features tile (32 x 64) -> shin[:,128:192] (lifetime-disjoint)
        int idx = tid + it * 256;
        int p = idx >> 6, f = idx & 63;
        shin[p * 256 + 128 + f] = features[(size_t)(pt0 + p) * FF + f];
    }
    if (tid < TILE) sc[tid] = gb[0];
    __syncthreads();

    float acc[4][4];

    // L1a: gelu(inv @ iW1 + ib1) -> bufA
    gemm_small<6, 8>(inv6, iW1, ib1, p0, c0, acc);
#pragma unroll
    for (int i = 0; i < 4; i++)
        store4f(&bufA[(p0 + i) * 128 + c0], gelu_exact(acc[i][0]), gelu_exact(acc[i][1]),
                gelu_exact(acc[i][2]), gelu_exact(acc[i][3]));
    __syncthreads();

    // L2a: bufA @ iW2 + ib2 -> shin[:, 0:128]
    gemm_lds<128, 128>(bufA, iW2, ib2, wbuf, tid, p0, c0, acc);
#pragma unroll
    for (int i = 0; i < 4; i++)
        store4f(&shin[(p0 + i) * 256 + c0], acc[i][0], acc[i][1], acc[i][2], acc[i][3]);
    __syncthreads();

    // L1b: gelu(feat @ fW1 + fb1) -> bufA   (features live at shin[:,128:192])
    gemm_lds<64, 256>(shin + 128, fW1, fb1, wbuf, tid, p0, c0, acc);
#pragma unroll
    for (int i = 0; i < 4; i++)
        store4f(&bufA[(p0 + i) * 128 + c0], gelu_exact(acc[i][0]), gelu_exact(acc[i][1]),
                gelu_exact(acc[i][2]), gelu_exact(acc[i][3]));
    __syncthreads();

    // L2b: bufA @ fW2 + fb2 -> shin[:, 128:256]  (overwrites features tile - done with it)
    gemm_lds<128, 128>(bufA, fW2, fb2, wbuf, tid, p0, c0, acc);
#pragma unroll
    for (int i = 0; i < 4; i++)
        store4f(&shin[(p0 + i) * 256 + 128 + c0], acc[i][0], acc[i][1], acc[i][2], acc[i][3]);
    __syncthreads();

    // L1c: gelu(shin @ sW1 + sb1) -> bufA
    gemm_lds<256, 256>(shin, sW1, sb1, wbuf, tid, p0, c0, acc);
#pragma unroll
    for (int i = 0; i < 4; i++)
        store4f(&bufA[(p0 + i) * 128 + c0], gelu_exact(acc[i][0]), gelu_exact(acc[i][1]),
                gelu_exact(acc[i][2]), gelu_exact(acc[i][3]));
    __syncthreads();

    // L2c: bufA @ sW2 + sb2 (in regs), then scalar = hidden @ g0_W + g0_b
    gemm_lds<128, 128>(bufA, sW2, sb2, wbuf, tid, p0, c0, acc);
    float4 g = *(const float4*)(gW + c0);
#pragma unroll
    for (int i = 0; i < 4; i++) {
        float s = acc[i][0] * g.x + acc[i][1] * g.y + acc[i][2] * g.z + acc[i][3] * g.w;
        atomicAdd(&sc[p0 + i], s);
    }
    __syncthreads();
    if (tid < TILE) out[(size_t)(pt0 + tid) * 16] = sc[tid];
}

// ---------------- launcher ----------------
extern "C" void kernel_launch(void* const* d_in, const int* in_sizes, int n_in,
                              void* d_out, int out_size, void* d_ws, size_t ws_size,
                              hipStream_t stream) {
    const float* coords   = (const float*)d_in[0];
    const float* features = (const float*)d_in[1];
    const float* iW1 = (const float*)d_in[2],  * ib1 = (const float*)d_in[3];
    const float* iW2 = (const float*)d_in[4],  * ib2 = (const float*)d_in[5];
    const float* fW1 = (const float*)d_in[6],  * fb1 = (const float*)d_in[7];
    const float* fW2 = (const float*)d_in[8],  * fb2 = (const float*)d_in[9];
    const float* sW1 = (const float*)d_in[10], * sb1 = (const float*)d_in[11];
    const float* sW2 = (const float*)d_in[12], * sb2 = (const float*)d_in[13];
    const float* gW  = (const float*)d_in[14], * gb  = (const float*)d_in[15];
    float* out = (float*)d_out;

    float* ws = (float*)d_ws;
    float4* coords4 = (float4*)ws;            // B*N float4
    float* center = ws + BB * NN * 4;         // B*4 floats
    float* invar  = center + 32;              // B*N*8 floats

    hipLaunchKernelGGL(k_prep, dim3(BB), dim3(256), 0, stream, coords, coords4, center);
    hipLaunchKernelGGL(k_knn, dim3(1024), dim3(256), 0, stream, coords4, center, invar, out);
    hipLaunchKernelGGL(k_mlp, dim3(1024), dim3(256), 0, stream, invar, features,
                       iW1, ib1, iW2, ib2, fW1, fb1, fW2, fb2, sW1, sb1, sW2, sb2, gW, gb, out);
}

// Round 13
// 302.024 us; speedup vs baseline: 1.3548x; 1.1387x over previous
//
#include <hip/hip_runtime.h>
#include <hip/hip_bf16.h>

#define BB 8
#define NN 4096
#define FF 64
#define HH 128
#define KNN 16

// ---- reference-matching arithmetic (XLA-CPU style: FMA-contracted dot/sq) ----
__device__ __forceinline__ float sq3(float x, float y, float z) {
    return fmaf(z, z, fmaf(y, y, __fmul_rn(x, x)));
}
__device__ __forceinline__ float dist2f(float px, float py, float pz, float psq, float4 cc) {
    float t = fmaf(pz, cc.z, fmaf(py, cc.y, __fmul_rn(px, cc.x)));
    return __fsub_rn(__fadd_rn(psq, cc.w), __fmul_rn(2.0f, t));
}

// ---------------- Kernel 1: pack coords + sq norm, compute per-batch center ----------------
extern "C" __global__ __launch_bounds__(256)
void k_prep(const float* __restrict__ coords, float4* __restrict__ coords4, float* __restrict__ center) {
    const int b = blockIdx.x, tid = threadIdx.x;
    __shared__ float rx[256], ry[256], rz[256];
    float sx = 0.f, sy = 0.f, sz = 0.f;
    for (int n = tid; n < NN; n += 256) {
        const float* c = coords + (size_t)(b * NN + n) * 3;
        float x = c[0], y = c[1], z = c[2];
        coords4[b * NN + n] = make_float4(x, y, z, sq3(x, y, z));
        sx += x; sy += y; sz += z;
    }
    rx[tid] = sx; ry[tid] = sy; rz[tid] = sz;
    __syncthreads();
    for (int s = 128; s > 0; s >>= 1) {
        if (tid < s) { rx[tid] += rx[tid + s]; ry[tid] += ry[tid + s]; rz[tid] += rz[tid + s]; }
        __syncthreads();
    }
    if (tid == 0) {
        center[b * 4 + 0] = rx[0] * (1.0f / NN);
        center[b * 4 + 1] = ry[0] * (1.0f / NN);
        center[b * 4 + 2] = rz[0] * (1.0f / NN);
    }
}

// Jacobi rotation on symmetric 3x3 (exact rotations, division-safe).
#define JROT(app, aqq, apq, arp, arq, vp0, vp1, vp2, vq0, vq1, vq2) { \
    float tau_ = (aqq - app) / (2.0f * apq); \
    float tt_ = copysignf(1.0f, tau_) / (fabsf(tau_) + sqrtf(1.0f + tau_ * tau_)); \
    if (apq == 0.0f) tt_ = 0.0f; \
    float cc_ = 1.0f / sqrtf(1.0f + tt_ * tt_); \
    float ss_ = tt_ * cc_; \
    float app_n = cc_*cc_*app - 2.0f*cc_*ss_*apq + ss_*ss_*aqq; \
    float aqq_n = ss_*ss_*app + 2.0f*cc_*ss_*apq + cc_*cc_*aqq; \
    float apq_n = cc_*ss_*(app - aqq) + (cc_*cc_ - ss_*ss_)*apq; \
    float arp_n = cc_*arp - ss_*arq; \
    float arq_n = ss_*arp + cc_*arq; \
    app = app_n; aqq = aqq_n; apq = apq_n; arp = arp_n; arq = arq_n; \
    float t0_ = cc_*vp0 - ss_*vq0, t1_ = cc_*vp1 - ss_*vq1, t2_ = cc_*vp2 - ss_*vq2; \
    vq0 = ss_*vp0 + cc_*vq0; vq1 = ss_*vp1 + cc_*vq1; vq2 = ss_*vp2 + cc_*vq2; \
    vp0 = t0_; vp1 = t1_; vp2 = t2_; }

#define SWAPF(a, b) { float sw_ = a; a = b; b = sw_; }

// Bitonic sort 16 floats ascending (80 compare-exchanges, exact multiset op).
__device__ __forceinline__ void sort16(float (&d)[16]) {
#pragma unroll
    for (int k = 2; k <= 16; k <<= 1) {
#pragma unroll
        for (int j = k >> 1; j > 0; j >>= 1) {
#pragma unroll
            for (int i = 0; i < 16; i++) {
                int l = i ^ j;
                if (l > i) {
                    if ((i & k) == 0) {
                        float mn = fminf(d[i], d[l]);
                        d[l] = fmaxf(d[i], d[l]);
                        d[i] = mn;
                    } else {
                        float mx = fmaxf(d[i], d[l]);
                        d[l] = fminf(d[i], d[l]);
                        d[i] = mx;
                    }
                }
            }
        }
    }
}

// dk (asc) + d (asc) -> dk = 16 smallest of the 32, ascending (Batcher halver + clean).
__device__ __forceinline__ void merge16(float (&dk)[16], const float (&d)[16]) {
    float t[16];
#pragma unroll
    for (int i = 0; i < 16; i++) t[i] = fminf(dk[i], d[15 - i]);
#pragma unroll
    for (int j = 8; j > 0; j >>= 1) {
#pragma unroll
        for (int i = 0; i < 16; i++) {
            int l = i ^ j;
            if (l > i) {
                float mn = fminf(t[i], t[l]);
                t[l] = fmaxf(t[i], t[l]);
                t[i] = mn;
            }
        }
    }
#pragma unroll
    for (int i = 0; i < 16; i++) dk[i] = t[i];
}

// ---------------- fused-kernel GEMM helpers ----------------
__device__ __forceinline__ float gelu_exact(float x) {
    return 0.5f * x * (1.0f + erff(x * 0.70710678118654752440f));
}

// Small-K GEMM (K=6), direct global W reads.
template <int KDIM, int LDA>
__device__ __forceinline__ void gemm_small(const float* A, const float* __restrict__ W,
                                           const float* __restrict__ bias, int p0, int c0, float acc[4][4]) {
    float4 bb = *(const float4*)(bias + c0);
#pragma unroll
    for (int i = 0; i < 4; i++) { acc[i][0] = bb.x; acc[i][1] = bb.y; acc[i][2] = bb.z; acc[i][3] = bb.w; }
#pragma unroll
    for (int k = 0; k < KDIM; k++) {
        float4 w = *(const float4*)(W + k * HH + c0);
#pragma unroll
        for (int i = 0; i < 4; i++) {
            float a = A[(p0 + i) * LDA + k];
            acc[i][0] = fmaf(a, w.x, acc[i][0]);
            acc[i][1] = fmaf(a, w.y, acc[i][1]);
            acc[i][2] = fmaf(a, w.z, acc[i][2]);
            acc[i][3] = fmaf(a, w.w, acc[i][3]);
        }
    }
}

// K%8==0 GEMM, chunk-8 W loads inside a NOT-unrolled loop (R7/R8: full unroll
// -> cross-chunk load hoisting -> scratch spill, 35x slowdown). INIT=false
// continues accumulation (for the two-stage concat GEMM) - same ascending-k
// chain as the original single K=256 loop, bitwise identical.
template <int KDIM, int LDA, bool INIT>
__device__ __forceinline__ void gemm_c8(const float* A, const float* __restrict__ Wg,
                                        const float* __restrict__ bias, int p0, int c0, float acc[4][4]) {
    static_assert(KDIM % 8 == 0, "KDIM must be a multiple of 8");
    if (INIT) {
        float4 bb = *(const float4*)(bias + c0);
#pragma unroll
        for (int i = 0; i < 4; i++) { acc[i][0] = bb.x; acc[i][1] = bb.y; acc[i][2] = bb.z; acc[i][3] = bb.w; }
    }
#pragma unroll 1
    for (int kk = 0; kk < KDIM; kk += 8) {
        const float* Wk = Wg + kk * HH + c0;
        float4 w0 = *(const float4*)(Wk + 0 * HH);
        float4 w1 = *(const float4*)(Wk + 1 * HH);
        float4 w2 = *(const float4*)(Wk + 2 * HH);
        float4 w3 = *(const float4*)(Wk + 3 * HH);
        float4 w4 = *(const float4*)(Wk + 4 * HH);
        float4 w5 = *(const float4*)(Wk + 5 * HH);
        float4 w6 = *(const float4*)(Wk + 6 * HH);
        float4 w7 = *(const float4*)(Wk + 7 * HH);
#pragma unroll
        for (int r = 0; r < 4; r++) {
            const float* Ar = A + (p0 + r) * LDA + kk;
            float4 t0 = *(const float4*)(Ar);
            float4 t1 = *(const float4*)(Ar + 4);
            acc[r][0] = fmaf(t0.x, w0.x, acc[r][0]);
            acc[r][1] = fmaf(t0.x, w0.y, acc[r][1]);
            acc[r][2] = fmaf(t0.x, w0.z, acc[r][2]);
            acc[r][3] = fmaf(t0.x, w0.w, acc[r][3]);
            acc[r][0] = fmaf(t0.y, w1.x, acc[r][0]);
            acc[r][1] = fmaf(t0.y, w1.y, acc[r][1]);
            acc[r][2] = fmaf(t0.y, w1.z, acc[r][2]);
            acc[r][3] = fmaf(t0.y, w1.w, acc[r][3]);
            acc[r][0] = fmaf(t0.z, w2.x, acc[r][0]);
            acc[r][1] = fmaf(t0.z, w2.y, acc[r][1]);
            acc[r][2] = fmaf(t0.z, w2.z, acc[r][2]);
            acc[r][3] = fmaf(t0.z, w2.w, acc[r][3]);
            acc[r][0] = fmaf(t0.w, w3.x, acc[r][0]);
            acc[r][1] = fmaf(t0.w, w3.y, acc[r][1]);
            acc[r][2] = fmaf(t0.w, w3.z, acc[r][2]);
            acc[r][3] = fmaf(t0.w, w3.w, acc[r][3]);
            acc[r][0] = fmaf(t1.x, w4.x, acc[r][0]);
            acc[r][1] = fmaf(t1.x, w4.y, acc[r][1]);
            acc[r][2] = fmaf(t1.x, w4.z, acc[r][2]);
            acc[r][3] = fmaf(t1.x, w4.w, acc[r][3]);
            acc[r][0] = fmaf(t1.y, w5.x, acc[r][0]);
            acc[r][1] = fmaf(t1.y, w5.y, acc[r][1]);
            acc[r][2] = fmaf(t1.y, w5.z, acc[r][2]);
            acc[r][3] = fmaf(t1.y, w5.w, acc[r][3]);
            acc[r][0] = fmaf(t1.z, w6.x, acc[r][0]);
            acc[r][1] = fmaf(t1.z, w6.y, acc[r][1]);
            acc[r][2] = fmaf(t1.z, w6.z, acc[r][2]);
            acc[r][3] = fmaf(t1.z, w6.w, acc[r][3]);
            acc[r][0] = fmaf(t1.w, w7.x, acc[r][0]);
            acc[r][1] = fmaf(t1.w, w7.y, acc[r][1]);
            acc[r][2] = fmaf(t1.w, w7.z, acc[r][2]);
            acc[r][3] = fmaf(t1.w, w7.w, acc[r][3]);
        }
    }
}

__device__ __forceinline__ void store4f(float* dst, float a, float b, float c, float d) {
    *(float4*)dst = make_float4(a, b, c, d);
}

// ---------------- Fused kernel: kNN + geometry + full MLP per 32-point block ----------------
// 1024 blocks x 256 threads. Phase 1 (kNN/geometry) identical to R12's k_knn.
// Phase 2 runs the whole MLP chain for the block's own 32 points - invariants
// stay in LDS, no global round-trip, and blocks in phase-1 (VALU-bound) overlap
// blocks in phase-2 (L2-latency-bound) on the same CU.
// LDS is phase-aliased: tile+ilist (33K) <-> bufX+bufY (32K); 34.9 KB total -> 4 blocks/CU.
extern "C" __global__ __launch_bounds__(256, 4)
void k_fused(const float4* __restrict__ coords4, const float* __restrict__ center,
             const float* __restrict__ features,
             const float* __restrict__ iW1, const float* __restrict__ ib1,
             const float* __restrict__ iW2, const float* __restrict__ ib2,
             const float* __restrict__ fW1, const float* __restrict__ fb1,
             const float* __restrict__ fW2, const float* __restrict__ fb2,
             const float* __restrict__ sW1, const float* __restrict__ sb1,
             const float* __restrict__ sW2, const float* __restrict__ sb2,
             const float* __restrict__ gW, const float* __restrict__ gb,
             float* __restrict__ out) {
    const int blk = blockIdx.x;
    const int b = blk >> 7;
    const int chunk = blk & 127;
    const int tid = threadIdx.x;
    const int pid = tid & 31;
    const int h = tid >> 5;
    const int n = chunk * 32 + pid;
    const float4* __restrict__ C = coords4 + b * NN;

    __shared__ __align__(16) char smem[34944];
    float4* tile = (float4*)smem;                  // [512]   8 KB   (phase 1)
    int* ilist = (int*)(smem + 8192);              // [6144] 24 KB   (phase 1; mb aliases)
    int* cnts = (int*)(smem + 32768);              // [256]   1 KB
    float* inv8 = (float*)(smem + 33792);          // [32*8]  1 KB   (epilogue -> phase 2)
    float* sc = (float*)(smem + 34816);            // [32]  128 B
    float* mb = (float*)ilist;
    float* bufX = (float*)smem;                    // [32*128] 16 KB (phase 2)
    float* bufY = (float*)(smem + 16384);          // [32*128] 16 KB (phase 2)

    float4 me = C[n];
    const float px = me.x, py = me.y, pz = me.z, psq = me.w;
    const float INF = __builtin_inff();

    // ======== PHASE 1: kNN (identical arithmetic to R12) ========
    float dk[KNN];
#pragma unroll
    for (int i = 0; i < KNN; i++) dk[i] = INF;

    for (int r = 0; r < 8; r++) {
        __syncthreads();
#pragma unroll
        for (int e = tid; e < 512; e += 256) {
            int seg = e >> 6, idx = e & 63;
            tile[e] = C[seg * 512 + r * 64 + idx];
        }
        __syncthreads();
        const float4* T = &tile[h * 64];
        const int selfj = n - (h * 512 + r * 64);
#pragma unroll
        for (int bt = 0; bt < 4; bt++) {
            float d[16];
#pragma unroll
            for (int i = 0; i < 16; i++) {
                float4 cc = T[bt * 16 + i];
                float dd = dist2f(px, py, pz, psq, cc);
                d[i] = (bt * 16 + i) == selfj ? INF : dd;
            }
            sort16(d);
            merge16(dk, d);
        }
    }

    // symmetric 8-way merge
    __syncthreads();
#pragma unroll
    for (int i = 0; i < KNN; i++) mb[tid * 17 + i] = dk[i];
    __syncthreads();
#pragma unroll
    for (int p = 1; p < 8; p++) {
        const int partner = (((h + p) & 7) << 5) + pid;
        float o[16];
#pragma unroll
        for (int i = 0; i < KNN; i++) o[i] = mb[partner * 17 + i];
        merge16(dk, o);
    }
    const float d15 = dk[15];

    // pass 2: index collection
    int cs = 0, ct = 0;
    const int lbase = (pid * 8 + h) * 24;
    for (int r = 0; r < 8; r++) {
        __syncthreads();
#pragma unroll
        for (int e = tid; e < 512; e += 256) {
            int seg = e >> 6, idx = e & 63;
            tile[e] = C[seg * 512 + r * 64 + idx];
        }
        __syncthreads();
        const float4* T = &tile[h * 64];
        const int base = h * 512 + r * 64;
#pragma unroll 4
        for (int j = 0; j < 64; j++) {
            float4 cc = T[j];
            float d = dist2f(px, py, pz, psq, cc);   // bitwise identical to pass 1
            int g = base + j;
            if (g != n && d <= d15) {
                if (d < d15) {
                    if (cs < 15) ilist[lbase + cs] = g;
                    cs++;
                } else if (ct < 8) {
                    ilist[lbase + 15 + ct] = g;
                    ct++;
                }
            }
        }
    }
    cnts[pid * 8 + h] = (cs & 0xff) | (ct << 8);
    __syncthreads();

    // ======== epilogue: geometry for 32 points (threads 0..31) ========
    if (h == 0) {
        int s[8], t8[8], sb[8], tb[8], cum[8], tcum[8];
#pragma unroll
        for (int q = 0; q < 8; q++) {
            int cp = cnts[pid * 8 + q];
            s[q] = cp & 0xff; t8[q] = cp >> 8;
            sb[q] = (pid * 8 + q) * 24; tb[q] = sb[q] + 15;
        }
        cum[0] = s[0]; tcum[0] = t8[0];
#pragma unroll
        for (int q = 1; q < 8; q++) { cum[q] = cum[q - 1] + s[q]; tcum[q] = tcum[q - 1] + t8[q]; }

        float cxx = 0.f, cxy = 0.f, cxz = 0.f, cyy = 0.f, cyz = 0.f, czz = 0.f, radsum = 0.f;
#pragma unroll
        for (int j = 0; j < KNN; j++) {
            int addr = sb[0] + j;
#pragma unroll
            for (int q = 1; q < 8; q++)
                if (j >= cum[q - 1]) addr = sb[q] + (j - cum[q - 1]);
            int jt = j - cum[7];
            if (j >= cum[7]) addr = tb[0] + jt;
#pragma unroll
            for (int q = 1; q < 8; q++)
                if (j >= cum[7] && jt >= tcum[q - 1]) addr = tb[q] + (jt - tcum[q - 1]);
            int id = ilist[addr];
            float4 cc = C[id];
            float rx = __fsub_rn(cc.x, px), ry = __fsub_rn(cc.y, py), rz = __fsub_rn(cc.z, pz);
            cxx = __fadd_rn(cxx, __fmul_rn(rx, rx));
            cxy = __fadd_rn(cxy, __fmul_rn(rx, ry));
            cxz = __fadd_rn(cxz, __fmul_rn(rx, rz));
            cyy = __fadd_rn(cyy, __fmul_rn(ry, ry));
            cyz = __fadd_rn(cyz, __fmul_rn(ry, rz));
            czz = __fadd_rn(czz, __fmul_rn(rz, rz));
            float rr = __fadd_rn(__fadd_rn(__fmul_rn(rx, rx), __fmul_rn(ry, ry)), __fmul_rn(rz, rz));
            radsum = __fadd_rn(radsum, sqrtf(rr));
        }
        const float inv_k = 1.0f / KNN;
        float a00 = cxx * inv_k, a01 = cxy * inv_k, a02 = cxz * inv_k;
        float a11 = cyy * inv_k, a12 = cyz * inv_k, a22 = czz * inv_k;

        float V00 = 1.f, V01 = 0.f, V02 = 0.f;
        float V10 = 0.f, V11 = 1.f, V12 = 0.f;
        float V20 = 0.f, V21 = 0.f, V22 = 1.f;
        for (int sweep = 0; sweep < 6; sweep++) {
            JROT(a00, a11, a01, a02, a12, V00, V10, V20, V01, V11, V21);
            JROT(a00, a22, a02, a01, a12, V00, V10, V20, V02, V12, V22);
            JROT(a11, a22, a12, a01, a02, V01, V11, V21, V02, V12, V22);
        }
        float e0 = a00, e1 = a11, e2 = a22;
        float x0 = V00, y0 = V10, z0 = V20;
        float x1 = V01, y1 = V11, z1 = V21;
        float x2 = V02, y2 = V12, z2 = V22;
        if (e0 > e1) { SWAPF(e0, e1); SWAPF(x0, x1); SWAPF(y0, y1); SWAPF(z0, z1); }
        if (e1 > e2) { SWAPF(e1, e2); SWAPF(x1, x2); SWAPF(y1, y2); SWAPF(z1, z2); }
        if (e0 > e1) { SWAPF(e0, e1); SWAPF(x0, x1); SWAPF(y0, y1); SWAPF(z0, z1); }

        float cx = center[b * 4 + 0], cy = center[b * 4 + 1], cz = center[b * 4 + 2];
        float ox = __fsub_rn(px, cx), oy = __fsub_rn(py, cy), oz = __fsub_rn(pz, cz);
        float dt = __fadd_rn(__fadd_rn(__fmul_rn(x0, ox), __fmul_rn(y0, oy)), __fmul_rn(z0, oz));
        float sgn = (dt >= 0.0f) ? 1.0f : -1.0f;
        x0 *= sgn; y0 *= sgn; z0 *= sgn;
        float nrm = sqrtf(__fadd_rn(__fadd_rn(__fmul_rn(x0, x0), __fmul_rn(y0, y0)), __fmul_rn(z0, z0)));
        float den = fmaxf(nrm, 1e-6f);
        x0 = x0 / den; y0 = y0 / den; z0 = z0 / den;

        float radius = radsum * inv_k;
        float crad = sqrtf(__fadd_rn(__fadd_rn(__fmul_rn(ox, ox), __fmul_rn(oy, oy)), __fmul_rn(oz, oz)));
        float esum = fmaxf(__fadd_rn(__fadd_rn(e0, e1), e2), 1e-6f);
        float dom = e2 / esum;

        // invariants -> LDS (consumed by phase 2; layout matches old invar)
        float* ip = inv8 + pid * 8;
        ip[0] = e0; ip[1] = e1; ip[2] = e2; ip[3] = radius; ip[4] = crad; ip[5] = dom;
        ip[6] = 0.f; ip[7] = 0.f;

        // output channels 1..15 (ch0 written at end of phase 2 by same thread)
        float pd = __fadd_rn(__fadd_rn(__fmul_rn(px, x0), __fmul_rn(py, y0)), __fmul_rn(pz, z0));
        float4* o = (float4*)(out + (size_t)(b * NN + n) * 16);
        o[0] = make_float4(0.0f, x0, y0, -z0);
        o[1] = make_float4(-pd, x0, y0, z0);
        o[2] = make_float4(0.0f, 0.0f, 0.0f, px);
        o[3] = make_float4(py, pz, 1.0f, 0.0f);
        sc[pid] = gb[0];
    }
    __syncthreads();   // phase boundary: ilist/tile dead, inv8/sc live

    // ======== PHASE 2: MLP for this block's 32 points ========
    const int cg = tid & 31, pg = tid >> 5;
    const int c0 = cg * 4, p0 = pg * 4;

    // features tile (32 x 64) -> bufY[:, 0:64] (stride 128)
#pragma unroll
    for (int it = 0; it < 8; it++) {
        int idx = tid + it * 256;
        int p = idx >> 6, f = idx & 63;
        bufY[p * HH + f] = features[(size_t)(b * NN + chunk * 32 + p) * FF + f];
    }
    __syncthreads();

    float acc[4][4];

    // L1a: gelu(inv @ iW1 + ib1) -> bufX
    gemm_small<6, 8>(inv8, iW1, ib1, p0, c0, acc);
#pragma unroll
    for (int i = 0; i < 4; i++)
        store4f(&bufX[(p0 + i) * HH + c0], gelu_exact(acc[i][0]), gelu_exact(acc[i][1]),
                gelu_exact(acc[i][2]), gelu_exact(acc[i][3]));
    __syncthreads();

    // L2a: bufX @ iW2 + ib2 -> inv_h; write back into bufX (read-drain barrier first)
    gemm_c8<128, 128, true>(bufX, iW2, ib2, p0, c0, acc);
    __syncthreads();
#pragma unroll
    for (int i = 0; i < 4; i++)
        store4f(&bufX[(p0 + i) * HH + c0], acc[i][0], acc[i][1], acc[i][2], acc[i][3]);
    __syncthreads();

    // L1b: gelu(feat @ fW1 + fb1); feat lives in bufY[:,0:64]; write h1_feat -> bufY
    gemm_c8<64, 128, true>(bufY, fW1, fb1, p0, c0, acc);
    __syncthreads();
#pragma unroll
    for (int i = 0; i < 4; i++)
        store4f(&bufY[(p0 + i) * HH + c0], gelu_exact(acc[i][0]), gelu_exact(acc[i][1]),
                gelu_exact(acc[i][2]), gelu_exact(acc[i][3]));
    __syncthreads();

    // L2b: bufY @ fW2 + fb2 -> feat_h; write back into bufY
    gemm_c8<128, 128, true>(bufY, fW2, fb2, p0, c0, acc);
    __syncthreads();
#pragma unroll
    for (int i = 0; i < 4; i++)
        store4f(&bufY[(p0 + i) * HH + c0], acc[i][0], acc[i][1], acc[i][2], acc[i][3]);
    __syncthreads();

    // L1c: gelu(concat(inv_h, feat_h) @ sW1 + sb1) - two-stage, same ascending-k chain
    gemm_c8<128, 128, true>(bufX, sW1, sb1, p0, c0, acc);
    gemm_c8<128, 128, false>(bufY, sW1 + 128 * HH, nullptr, p0, c0, acc);
    __syncthreads();
#pragma unroll
    for (int i = 0; i < 4; i++)
        store4f(&bufX[(p0 + i) * HH + c0], gelu_exact(acc[i][0]), gelu_exact(acc[i][1]),
                gelu_exact(acc[i][2]), gelu_exact(acc[i][3]));
    __syncthreads();

    // L2c: bufX @ sW2 + sb2 (in regs), then scalar = hidden @ g0_W + g0_b
    gemm_c8<128, 128, true>(bufX, sW2, sb2, p0, c0, acc);
    float4 g = *(const float4*)(gW + c0);
#pragma unroll
    for (int i = 0; i < 4; i++) {
        float s = acc[i][0] * g.x + acc[i][1] * g.y + acc[i][2] * g.z + acc[i][3] * g.w;
        atomicAdd(&sc[p0 + i], s);
    }
    __syncthreads();
    if (tid < 32) out[(size_t)(b * NN + n) * 16] = sc[tid];
}

// ---------------- launcher ----------------
extern "C" void kernel_launch(void* const* d_in, const int* in_sizes, int n_in,
                              void* d_out, int out_size, void* d_ws, size_t ws_size,
                              hipStream_t stream) {
    const float* coords   = (const float*)d_in[0];
    const float* features = (const float*)d_in[1];
    const float* iW1 = (const float*)d_in[2],  * ib1 = (const float*)d_in[3];
    const float* iW2 = (const float*)d_in[4],  * ib2 = (const float*)d_in[5];
    const float* fW1 = (const float*)d_in[6],  * fb1 = (const float*)d_in[7];
    const float* fW2 = (const float*)d_in[8],  * fb2 = (const float*)d_in[9];
    const float* sW1 = (const float*)d_in[10], * sb1 = (const float*)d_in[11];
    const float* sW2 = (const float*)d_in[12], * sb2 = (const float*)d_in[13];
    const float* gW  = (const float*)d_in[14], * gb  = (const float*)d_in[15];
    float* out = (float*)d_out;

    float* ws = (float*)d_ws;
    float4* coords4 = (float4*)ws;            // B*N float4
    float* center = ws + BB * NN * 4;         // B*4 floats

    hipLaunchKernelGGL(k_prep, dim3(BB), dim3(256), 0, stream, coords, coords4, center);
    hipLaunchKernelGGL(k_fused, dim3(1024), dim3(256), 0, stream, coords4, center, features,
                       iW1, ib1, iW2, ib2, fW1, fb1, fW2, fb2, sW1, sb1, sW2, sb2, gW, gb, out);
}

// Round 14
// 286.729 us; speedup vs baseline: 1.4270x; 1.0533x over previous
//
#include <hip/hip_runtime.h>
#include <hip/hip_bf16.h>

#define BB 8
#define NN 4096
#define FF 64
#define HH 128
#define KNN 16

typedef __attribute__((ext_vector_type(8))) short bf16x8;
typedef __attribute__((ext_vector_type(4))) float f32x4;

// Fragment-ordered bf16 weight workspace offsets (in shorts)
#define OFF_iW2 0
#define OFF_fW1 16384
#define OFF_fW2 24576
#define OFF_sW1 40960
#define OFF_sW2 73728
#define HI_SZ   90112

// ---- reference-matching arithmetic (XLA-CPU style: FMA-contracted dot/sq) ----
__device__ __forceinline__ float sq3(float x, float y, float z) {
    return fmaf(z, z, fmaf(y, y, __fmul_rn(x, x)));
}
__device__ __forceinline__ float dist2f(float px, float py, float pz, float psq, float4 cc) {
    float t = fmaf(pz, cc.z, fmaf(py, cc.y, __fmul_rn(px, cc.x)));
    return __fsub_rn(__fadd_rn(psq, cc.w), __fmul_rn(2.0f, t));
}

// round-to-nearest-even f32 -> bf16 bits (finite inputs)
__device__ __forceinline__ short f2bf(float x) {
    unsigned u = __float_as_uint(x);
    u += 0x7fffu + ((u >> 16) & 1u);
    return (short)(u >> 16);
}
__device__ __forceinline__ float bf2f(short s) {
    return __uint_as_float(((unsigned)(unsigned short)s) << 16);
}

// ---------------- Kernel 1: pack coords + sq norm, per-batch center ----------------
extern "C" __global__ __launch_bounds__(256)
void k_prep(const float* __restrict__ coords, float4* __restrict__ coords4, float* __restrict__ center) {
    const int b = blockIdx.x, tid = threadIdx.x;
    __shared__ float rx[256], ry[256], rz[256];
    float sx = 0.f, sy = 0.f, sz = 0.f;
    for (int n = tid; n < NN; n += 256) {
        const float* c = coords + (size_t)(b * NN + n) * 3;
        float x = c[0], y = c[1], z = c[2];
        coords4[b * NN + n] = make_float4(x, y, z, sq3(x, y, z));
        sx += x; sy += y; sz += z;
    }
    rx[tid] = sx; ry[tid] = sy; rz[tid] = sz;
    __syncthreads();
    for (int s = 128; s > 0; s >>= 1) {
        if (tid < s) { rx[tid] += rx[tid + s]; ry[tid] += ry[tid + s]; rz[tid] += rz[tid + s]; }
        __syncthreads();
    }
    if (tid == 0) {
        center[b * 4 + 0] = rx[0] * (1.0f / NN);
        center[b * 4 + 1] = ry[0] * (1.0f / NN);
        center[b * 4 + 2] = rz[0] * (1.0f / NN);
    }
}

// ---------------- Kernel 1b: split weights into hi/lo bf16, MFMA-fragment-ordered ----------------
// B-fragment for mfma_f32_16x16x32_bf16: lane holds B[k = (lane>>4)*8 + j][n = lane&15].
// Stream layout: elem e -> j=e&7, lane=(e>>3)&63, ct=(e>>9)&7, kb=e>>12;
// k = kb*32+(lane>>4)*8+j, n = ct*16+(lane&15).  16B per lane, coalesced loads.
extern "C" __global__ __launch_bounds__(256)
void k_wprep(const float* __restrict__ iW2, const float* __restrict__ fW1,
             const float* __restrict__ fW2, const float* __restrict__ sW1,
             const float* __restrict__ sW2, short* __restrict__ wbf) {
    const int w = blockIdx.y;
    const float* W; int K; int off;
    if (w == 0)      { W = iW2; K = 128; off = OFF_iW2; }
    else if (w == 1) { W = fW1; K = 64;  off = OFF_fW1; }
    else if (w == 2) { W = fW2; K = 128; off = OFF_fW2; }
    else if (w == 3) { W = sW1; K = 256; off = OFF_sW1; }
    else             { W = sW2; K = 128; off = OFF_sW2; }
    short* hi = wbf + off;
    short* lo = wbf + HI_SZ + off;
    const int total = K * 128;
    for (int e = blockIdx.x * 256 + threadIdx.x; e < total; e += gridDim.x * 256) {
        int j = e & 7, lane = (e >> 3) & 63, ct = (e >> 9) & 7, kb = e >> 12;
        int k = kb * 32 + (lane >> 4) * 8 + j;
        int n = ct * 16 + (lane & 15);
        float v = W[k * 128 + n];
        short h = f2bf(v);
        float r = v - bf2f(h);
        hi[e] = h; lo[e] = f2bf(r);
    }
}

// Jacobi rotation on symmetric 3x3 (exact rotations, division-safe).
#define JROT(app, aqq, apq, arp, arq, vp0, vp1, vp2, vq0, vq1, vq2) { \
    float tau_ = (aqq - app) / (2.0f * apq); \
    float tt_ = copysignf(1.0f, tau_) / (fabsf(tau_) + sqrtf(1.0f + tau_ * tau_)); \
    if (apq == 0.0f) tt_ = 0.0f; \
    float cc_ = 1.0f / sqrtf(1.0f + tt_ * tt_); \
    float ss_ = tt_ * cc_; \
    float app_n = cc_*cc_*app - 2.0f*cc_*ss_*apq + ss_*ss_*aqq; \
    float aqq_n = ss_*ss_*app + 2.0f*cc_*ss_*apq + cc_*cc_*aqq; \
    float apq_n = cc_*ss_*(app - aqq) + (cc_*cc_ - ss_*ss_)*apq; \
    float arp_n = cc_*arp - ss_*arq; \
    float arq_n = ss_*arp + cc_*arq; \
    app = app_n; aqq = aqq_n; apq = apq_n; arp = arp_n; arq = arq_n; \
    float t0_ = cc_*vp0 - ss_*vq0, t1_ = cc_*vp1 - ss_*vq1, t2_ = cc_*vp2 - ss_*vq2; \
    vq0 = ss_*vp0 + cc_*vq0; vq1 = ss_*vp1 + cc_*vq1; vq2 = ss_*vp2 + cc_*vq2; \
    vp0 = t0_; vp1 = t1_; vp2 = t2_; }

#define SWAPF(a, b) { float sw_ = a; a = b; b = sw_; }

// Bitonic sort 16 floats ascending (80 compare-exchanges, exact multiset op).
__device__ __forceinline__ void sort16(float (&d)[16]) {
#pragma unroll
    for (int k = 2; k <= 16; k <<= 1) {
#pragma unroll
        for (int j = k >> 1; j > 0; j >>= 1) {
#pragma unroll
            for (int i = 0; i < 16; i++) {
                int l = i ^ j;
                if (l > i) {
                    if ((i & k) == 0) {
                        float mn = fminf(d[i], d[l]);
                        d[l] = fmaxf(d[i], d[l]);
                        d[i] = mn;
                    } else {
                        float mx = fmaxf(d[i], d[l]);
                        d[l] = fminf(d[i], d[l]);
                        d[i] = mx;
                    }
                }
            }
        }
    }
}

// dk (asc) + d (asc) -> dk = 16 smallest of the 32, ascending.
__device__ __forceinline__ void merge16(float (&dk)[16], const float (&d)[16]) {
    float t[16];
#pragma unroll
    for (int i = 0; i < 16; i++) t[i] = fminf(dk[i], d[15 - i]);
#pragma unroll
    for (int j = 8; j > 0; j >>= 1) {
#pragma unroll
        for (int i = 0; i < 16; i++) {
            int l = i ^ j;
            if (l > i) {
                float mn = fminf(t[i], t[l]);
                t[l] = fmaxf(t[i], t[l]);
                t[i] = mn;
            }
        }
    }
#pragma unroll
    for (int i = 0; i < 16; i++) dk[i] = t[i];
}

// ---------------- MLP helpers ----------------
__device__ __forceinline__ float gelu_exact(float x) {
    return 0.5f * x * (1.0f + erff(x * 0.70710678118654752440f));
}

// Small-K GEMM (K=6), f32 VALU (tiny).
template <int KDIM, int LDA>
__device__ __forceinline__ void gemm_small(const float* A, const float* __restrict__ W,
                                           const float* __restrict__ bias, int p0, int c0, float acc[4][4]) {
    float4 bb = *(const float4*)(bias + c0);
#pragma unroll
    for (int i = 0; i < 4; i++) { acc[i][0] = bb.x; acc[i][1] = bb.y; acc[i][2] = bb.z; acc[i][3] = bb.w; }
#pragma unroll
    for (int k = 0; k < KDIM; k++) {
        float4 w = *(const float4*)(W + k * HH + c0);
#pragma unroll
        for (int i = 0; i < 4; i++) {
            float a = A[(p0 + i) * LDA + k];
            acc[i][0] = fmaf(a, w.x, acc[i][0]);
            acc[i][1] = fmaf(a, w.y, acc[i][1]);
            acc[i][2] = fmaf(a, w.z, acc[i][2]);
            acc[i][3] = fmaf(a, w.w, acc[i][3]);
        }
    }
}

// MFMA GEMM: C[32][128] += A[32][K] @ W[K][128], A bf16-hi in LDS [32][136],
// W exact via hi+lo bf16 fragment streams. Wave w owns col-tiles 2w, 2w+1, both
// row-tiles. A-layout: lane holds A[m=lane&15][k=quad*8+j] (guide §3, m89-verified);
// C/D: col=lane&15, row=quad*4+reg. unroll 1 per R7/R8 spill lesson.
template <int KB, bool INIT>
__device__ __forceinline__ void gemm_mfma(const short* Ab, const short* __restrict__ whi,
                                          const short* __restrict__ wlo,
                                          const float* __restrict__ bias,
                                          int wid, int lane, f32x4 acc[2][2]) {
    const int m16 = lane & 15, quad = lane >> 4;
    if (INIT) {
        float b0 = bias[(wid * 2 + 0) * 16 + m16];
        float b1 = bias[(wid * 2 + 1) * 16 + m16];
        acc[0][0] = (f32x4){b0, b0, b0, b0}; acc[1][0] = acc[0][0];
        acc[0][1] = (f32x4){b1, b1, b1, b1}; acc[1][1] = acc[0][1];
    }
#pragma unroll 1
    for (int kb = 0; kb < KB; kb++) {
        bf16x8 a0 = *(const bf16x8*)(Ab + m16 * 136 + kb * 32 + quad * 8);
        bf16x8 a1 = *(const bf16x8*)(Ab + (m16 + 16) * 136 + kb * 32 + quad * 8);
#pragma unroll
        for (int c = 0; c < 2; c++) {
            const int off = ((kb * 8 + wid * 2 + c) * 64 + lane) * 8;
            bf16x8 bh = *(const bf16x8*)(whi + off);
            bf16x8 bl = *(const bf16x8*)(wlo + off);
            acc[0][c] = __builtin_amdgcn_mfma_f32_16x16x32_bf16(a0, bh, acc[0][c], 0, 0, 0);
            acc[0][c] = __builtin_amdgcn_mfma_f32_16x16x32_bf16(a0, bl, acc[0][c], 0, 0, 0);
            acc[1][c] = __builtin_amdgcn_mfma_f32_16x16x32_bf16(a1, bh, acc[1][c], 0, 0, 0);
            acc[1][c] = __builtin_amdgcn_mfma_f32_16x16x32_bf16(a1, bl, acc[1][c], 0, 0, 0);
        }
    }
}

__device__ __forceinline__ void acc_to_stage(float* fstage, f32x4 acc[2][2], int wid, int lane, bool dogelu) {
    const int m16 = lane & 15, quad = lane >> 4;
#pragma unroll
    for (int mt = 0; mt < 2; mt++)
#pragma unroll
        for (int c = 0; c < 2; c++)
#pragma unroll
            for (int i = 0; i < 4; i++) {
                float v = acc[mt][c][i];
                if (dogelu) v = gelu_exact(v);
                fstage[(mt * 16 + quad * 4 + i) * 128 + (wid * 2 + c) * 16 + m16] = v;
            }
}

// fstage f32 [32][128] -> bf16-hi LDS [32][136] (512 chunks of 8)
__device__ __forceinline__ void cvt_stage(const float* fstage, short* dst, int tid) {
#pragma unroll
    for (int it = 0; it < 2; it++) {
        int idx = tid + it * 256;
        int row = idx >> 4, c8 = (idx & 15) * 8;
        const float* s = fstage + row * 128 + c8;
        float4 v0 = *(const float4*)s, v1 = *(const float4*)(s + 4);
        bf16x8 pk;
        pk[0] = f2bf(v0.x); pk[1] = f2bf(v0.y); pk[2] = f2bf(v0.z); pk[3] = f2bf(v0.w);
        pk[4] = f2bf(v1.x); pk[5] = f2bf(v1.y); pk[6] = f2bf(v1.z); pk[7] = f2bf(v1.w);
        *(bf16x8*)(dst + row * 136 + c8) = pk;
    }
}

__device__ __forceinline__ void store4f(float* dst, float a, float b, float c, float d) {
    *(float4*)dst = make_float4(a, b, c, d);
}

// ---------------- Fused kernel: kNN + geometry + MFMA MLP per 32-point block ----------------
extern "C" __global__ __launch_bounds__(256, 4)
void k_fused(const float4* __restrict__ coords4, const float* __restrict__ center,
             const float* __restrict__ features, const short* __restrict__ wbf,
             const float* __restrict__ iW1, const float* __restrict__ ib1,
             const float* __restrict__ ib2,
             const float* __restrict__ fb1, const float* __restrict__ fb2,
             const float* __restrict__ sb1, const float* __restrict__ sb2,
             const float* __restrict__ gW, const float* __restrict__ gb,
             float* __restrict__ out) {
    const int blk = blockIdx.x;
    const int b = blk >> 7;
    const int chunk = blk & 127;
    const int tid = threadIdx.x;
    const int pid = tid & 31;
    const int h = tid >> 5;
    const int n = chunk * 32 + pid;
    const float4* __restrict__ C = coords4 + b * NN;

    __shared__ __align__(16) char smem[34944];
    float4* tile = (float4*)smem;                  // [512]   8 KB  (phase 1)
    int* ilist = (int*)(smem + 8192);              // 24 KB         (phase 1)
    int* cnts = (int*)(smem + 32768);              // 1 KB          (phase 1 + epilogue only)
    float* inv8 = (float*)(smem + 33792);          // 1 KB          (epilogue -> phase 2)
    float* sc = (float*)(smem + 34816);            // 128 B
    float* mb = (float*)ilist;
    // phase-2 aliases (tile/ilist/cnts dead after epilogue):
    float* fstage = (float*)smem;                  // [32][128] f32, 16 KB  (0..16384)
    short* Abf = (short*)(smem + 16384);           // [32][136] bf16, 8704 B
    short* FHbf = (short*)(smem + 25088);          // [32][136] bf16, 8704 B (ends 33792)

    float4 me = C[n];
    const float px = me.x, py = me.y, pz = me.z, psq = me.w;
    const float INF = __builtin_inff();

    // ======== PHASE 1: kNN (bitwise identical to R13) ========
    float dk[KNN];
#pragma unroll
    for (int i = 0; i < KNN; i++) dk[i] = INF;

    for (int r = 0; r < 8; r++) {
        __syncthreads();
#pragma unroll
        for (int e = tid; e < 512; e += 256) {
            int seg = e >> 6, idx = e & 63;
            tile[e] = C[seg * 512 + r * 64 + idx];
        }
        __syncthreads();
        const float4* T = &tile[h * 64];
        const int selfj = n - (h * 512 + r * 64);
#pragma unroll
        for (int bt = 0; bt < 4; bt++) {
            float d[16];
#pragma unroll
            for (int i = 0; i < 16; i++) {
                float4 cc = T[bt * 16 + i];
                float dd = dist2f(px, py, pz, psq, cc);
                d[i] = (bt * 16 + i) == selfj ? INF : dd;
            }
            sort16(d);
            merge16(dk, d);
        }
    }

    __syncthreads();
#pragma unroll
    for (int i = 0; i < KNN; i++) mb[tid * 17 + i] = dk[i];
    __syncthreads();
#pragma unroll
    for (int p = 1; p < 8; p++) {
        const int partner = (((h + p) & 7) << 5) + pid;
        float o[16];
#pragma unroll
        for (int i = 0; i < KNN; i++) o[i] = mb[partner * 17 + i];
        merge16(dk, o);
    }
    const float d15 = dk[15];

    int cs = 0, ct = 0;
    const int lbase = (pid * 8 + h) * 24;
    for (int r = 0; r < 8; r++) {
        __syncthreads();
#pragma unroll
        for (int e = tid; e < 512; e += 256) {
            int seg = e >> 6, idx = e & 63;
            tile[e] = C[seg * 512 + r * 64 + idx];
        }
        __syncthreads();
        const float4* T = &tile[h * 64];
        const int base = h * 512 + r * 64;
#pragma unroll 4
        for (int j = 0; j < 64; j++) {
            float4 cc = T[j];
            float d = dist2f(px, py, pz, psq, cc);
            int g = base + j;
            if (g != n && d <= d15) {
                if (d < d15) {
                    if (cs < 15) ilist[lbase + cs] = g;
                    cs++;
                } else if (ct < 8) {
                    ilist[lbase + 15 + ct] = g;
                    ct++;
                }
            }
        }
    }
    cnts[pid * 8 + h] = (cs & 0xff) | (ct << 8);
    __syncthreads();

    // ======== epilogue: geometry (threads 0..31) ========
    if (h == 0) {
        int s[8], t8[8], sb[8], tb[8], cum[8], tcum[8];
#pragma unroll
        for (int q = 0; q < 8; q++) {
            int cp = cnts[pid * 8 + q];
            s[q] = cp & 0xff; t8[q] = cp >> 8;
            sb[q] = (pid * 8 + q) * 24; tb[q] = sb[q] + 15;
        }
        cum[0] = s[0]; tcum[0] = t8[0];
#pragma unroll
        for (int q = 1; q < 8; q++) { cum[q] = cum[q - 1] + s[q]; tcum[q] = tcum[q - 1] + t8[q]; }

        float cxx = 0.f, cxy = 0.f, cxz = 0.f, cyy = 0.f, cyz = 0.f, czz = 0.f, radsum = 0.f;
#pragma unroll
        for (int j = 0; j < KNN; j++) {
            int addr = sb[0] + j;
#pragma unroll
            for (int q = 1; q < 8; q++)
                if (j >= cum[q - 1]) addr = sb[q] + (j - cum[q - 1]);
            int jt = j - cum[7];
            if (j >= cum[7]) addr = tb[0] + jt;
#pragma unroll
            for (int q = 1; q < 8; q++)
                if (j >= cum[7] && jt >= tcum[q - 1]) addr = tb[q] + (jt - tcum[q - 1]);
            int id = ilist[addr];
            float4 cc = C[id];
            float rx = __fsub_rn(cc.x, px), ry = __fsub_rn(cc.y, py), rz = __fsub_rn(cc.z, pz);
            cxx = __fadd_rn(cxx, __fmul_rn(rx, rx));
            cxy = __fadd_rn(cxy, __fmul_rn(rx, ry));
            cxz = __fadd_rn(cxz, __fmul_rn(rx, rz));
            cyy = __fadd_rn(cyy, __fmul_rn(ry, ry));
            cyz = __fadd_rn(cyz, __fmul_rn(ry, rz));
            czz = __fadd_rn(czz, __fmul_rn(rz, rz));
            float rr = __fadd_rn(__fadd_rn(__fmul_rn(rx, rx), __fmul_rn(ry, ry)), __fmul_rn(rz, rz));
            radsum = __fadd_rn(radsum, sqrtf(rr));
        }
        const float inv_k = 1.0f / KNN;
        float a00 = cxx * inv_k, a01 = cxy * inv_k, a02 = cxz * inv_k;
        float a11 = cyy * inv_k, a12 = cyz * inv_k, a22 = czz * inv_k;

        float V00 = 1.f, V01 = 0.f, V02 = 0.f;
        float V10 = 0.f, V11 = 1.f, V12 = 0.f;
        float V20 = 0.f, V21 = 0.f, V22 = 1.f;
        for (int sweep = 0; sweep < 6; sweep++) {
            JROT(a00, a11, a01, a02, a12, V00, V10, V20, V01, V11, V21);
            JROT(a00, a22, a02, a01, a12, V00, V10, V20, V02, V12, V22);
            JROT(a11, a22, a12, a01, a02, V01, V11, V21, V02, V12, V22);
        }
        float e0 = a00, e1 = a11, e2 = a22;
        float x0 = V00, y0 = V10, z0 = V20;
        float x1 = V01, y1 = V11, z1 = V21;
        float x2 = V02, y2 = V12, z2 = V22;
        if (e0 > e1) { SWAPF(e0, e1); SWAPF(x0, x1); SWAPF(y0, y1); SWAPF(z0, z1); }
        if (e1 > e2) { SWAPF(e1, e2); SWAPF(x1, x2); SWAPF(y1, y2); SWAPF(z1, z2); }
        if (e0 > e1) { SWAPF(e0, e1); SWAPF(x0, x1); SWAPF(y0, y1); SWAPF(z0, z1); }

        float cx = center[b * 4 + 0], cy = center[b * 4 + 1], cz = center[b * 4 + 2];
        float ox = __fsub_rn(px, cx), oy = __fsub_rn(py, cy), oz = __fsub_rn(pz, cz);
        float dt = __fadd_rn(__fadd_rn(__fmul_rn(x0, ox), __fmul_rn(y0, oy)), __fmul_rn(z0, oz));
        float sgn = (dt >= 0.0f) ? 1.0f : -1.0f;
        x0 *= sgn; y0 *= sgn; z0 *= sgn;
        float nrm = sqrtf(__fadd_rn(__fadd_rn(__fmul_rn(x0, x0), __fmul_rn(y0, y0)), __fmul_rn(z0, z0)));
        float den = fmaxf(nrm, 1e-6f);
        x0 = x0 / den; y0 = y0 / den; z0 = z0 / den;

        float radius = radsum * inv_k;
        float crad = sqrtf(__fadd_rn(__fadd_rn(__fmul_rn(ox, ox), __fmul_rn(oy, oy)), __fmul_rn(oz, oz)));
        float esum = fmaxf(__fadd_rn(__fadd_rn(e0, e1), e2), 1e-6f);
        float dom = e2 / esum;

        float* ip = inv8 + pid * 8;
        ip[0] = e0; ip[1] = e1; ip[2] = e2; ip[3] = radius; ip[4] = crad; ip[5] = dom;
        ip[6] = 0.f; ip[7] = 0.f;

        float pd = __fadd_rn(__fadd_rn(__fmul_rn(px, x0), __fmul_rn(py, y0)), __fmul_rn(pz, z0));
        float4* o = (float4*)(out + (size_t)(b * NN + n) * 16);
        o[0] = make_float4(0.0f, x0, y0, -z0);
        o[1] = make_float4(-pd, x0, y0, z0);
        o[2] = make_float4(0.0f, 0.0f, 0.0f, px);
        o[3] = make_float4(py, pz, 1.0f, 0.0f);
        sc[pid] = gb[0];
    }
    __syncthreads();   // phase boundary: tile/ilist/cnts dead; inv8/sc live

    // ======== PHASE 2: MFMA MLP ========
    const int wid = tid >> 6, lane = tid & 63;
    const short* w_iW2h = wbf + OFF_iW2; const short* w_iW2l = wbf + HI_SZ + OFF_iW2;
    const short* w_fW1h = wbf + OFF_fW1; const short* w_fW1l = wbf + HI_SZ + OFF_fW1;
    const short* w_fW2h = wbf + OFF_fW2; const short* w_fW2l = wbf + HI_SZ + OFF_fW2;
    const short* w_sW1h = wbf + OFF_sW1; const short* w_sW1l = wbf + HI_SZ + OFF_sW1;
    const short* w_sW2h = wbf + OFF_sW2; const short* w_sW2l = wbf + HI_SZ + OFF_sW2;
    f32x4 acc[2][2];

    // s1: features (32 x 64) -> Abf bf16
    {
        int row = tid >> 3, c8 = (tid & 7) * 8;
        const float* s = features + (size_t)(b * NN + chunk * 32 + row) * FF + c8;
        float4 v0 = *(const float4*)s, v1 = *(const float4*)(s + 4);
        bf16x8 pk;
        pk[0] = f2bf(v0.x); pk[1] = f2bf(v0.y); pk[2] = f2bf(v0.z); pk[3] = f2bf(v0.w);
        pk[4] = f2bf(v1.x); pk[5] = f2bf(v1.y); pk[6] = f2bf(v1.z); pk[7] = f2bf(v1.w);
        *(bf16x8*)(Abf + row * 136 + c8) = pk;
    }
    __syncthreads();

    // s2: L1b = gelu(feat @ fW1 + fb1)
    gemm_mfma<2, true>(Abf, w_fW1h, w_fW1l, fb1, wid, lane, acc);
    acc_to_stage(fstage, acc, wid, lane, true);
    __syncthreads();
    cvt_stage(fstage, Abf, tid);
    __syncthreads();

    // s4: L2b = (h @ fW2 + fb2) -> feat_h -> FHbf
    gemm_mfma<4, true>(Abf, w_fW2h, w_fW2l, fb2, wid, lane, acc);
    acc_to_stage(fstage, acc, wid, lane, false);
    __syncthreads();
    cvt_stage(fstage, FHbf, tid);
    __syncthreads();

    // s6: L1a = gelu(inv @ iW1 + ib1)  (K=6, VALU)
    {
        const int cg = tid & 31, pg = tid >> 5;
        const int c0 = cg * 4, p0 = pg * 4;
        float a4[4][4];
        gemm_small<6, 8>(inv8, iW1, ib1, p0, c0, a4);
#pragma unroll
        for (int i = 0; i < 4; i++)
            store4f(&fstage[(p0 + i) * 128 + c0], gelu_exact(a4[i][0]), gelu_exact(a4[i][1]),
                    gelu_exact(a4[i][2]), gelu_exact(a4[i][3]));
    }
    __syncthreads();
    cvt_stage(fstage, Abf, tid);
    __syncthreads();

    // s8: L2a = (h @ iW2 + ib2) -> inv_h
    gemm_mfma<4, true>(Abf, w_iW2h, w_iW2l, ib2, wid, lane, acc);
    acc_to_stage(fstage, acc, wid, lane, false);
    __syncthreads();
    cvt_stage(fstage, Abf, tid);
    __syncthreads();

    // s10: L1c = gelu(concat(inv_h, feat_h) @ sW1 + sb1)  (two-stage K=128+128)
    gemm_mfma<4, true>(Abf, w_sW1h, w_sW1l, sb1, wid, lane, acc);
    gemm_mfma<4, false>(FHbf, w_sW1h + 16384, w_sW1l + 16384, nullptr, wid, lane, acc);
    acc_to_stage(fstage, acc, wid, lane, true);
    __syncthreads();
    cvt_stage(fstage, Abf, tid);
    __syncthreads();

    // s12: L2c = (h @ sW2 + sb2); scalar = hidden @ gW + gb
    gemm_mfma<4, true>(Abf, w_sW2h, w_sW2l, sb2, wid, lane, acc);
    {
        const int m16 = lane & 15, quad = lane >> 4;
#pragma unroll
        for (int mt = 0; mt < 2; mt++)
#pragma unroll
            for (int c = 0; c < 2; c++) {
                float g = gW[(wid * 2 + c) * 16 + m16];
#pragma unroll
                for (int i = 0; i < 4; i++)
                    atomicAdd(&sc[mt * 16 + quad * 4 + i], acc[mt][c][i] * g);
            }
    }
    __syncthreads();
    if (tid < 32) out[(size_t)(b * NN + n) * 16] = sc[tid];
}

// ---------------- launcher ----------------
extern "C" void kernel_launch(void* const* d_in, const int* in_sizes, int n_in,
                              void* d_out, int out_size, void* d_ws, size_t ws_size,
                              hipStream_t stream) {
    const float* coords   = (const float*)d_in[0];
    const float* features = (const float*)d_in[1];
    const float* iW1 = (const float*)d_in[2],  * ib1 = (const float*)d_in[3];
    const float* iW2 = (const float*)d_in[4],  * ib2 = (const float*)d_in[5];
    const float* fW1 = (const float*)d_in[6],  * fb1 = (const float*)d_in[7];
    const float* fW2 = (const float*)d_in[8],  * fb2 = (const float*)d_in[9];
    const float* sW1 = (const float*)d_in[10], * sb1 = (const float*)d_in[11];
    const float* sW2 = (const float*)d_in[12], * sb2 = (const float*)d_in[13];
    const float* gW  = (const float*)d_in[14], * gb  = (const float*)d_in[15];
    float* out = (float*)d_out;

    float* ws = (float*)d_ws;
    float4* coords4 = (float4*)ws;                        // 8*4096 float4 = 512 KB
    float* center = ws + BB * NN * 4;                     // 32 floats
    short* wbf = (short*)((char*)d_ws + 524416);          // 2*90112 shorts = 352 KB

    hipLaunchKernelGGL(k_prep, dim3(BB), dim3(256), 0, stream, coords, coords4, center);
    hipLaunchKernelGGL(k_wprep, dim3(16, 5), dim3(256), 0, stream, iW2, fW1, fW2, sW1, sW2, wbf);
    hipLaunchKernelGGL(k_fused, dim3(1024), dim3(256), 0, stream, coords4, center, features, wbf,
                       iW1, ib1, ib2, fb1, fb2, sb1, sb2, gW, gb, out);
}